// Round 7
// baseline (1547.976 us; speedup 1.0000x reference)
//
#include <hip/hip_runtime.h>
#include <math.h>

typedef unsigned short u16;
typedef unsigned int   u32;

#define B_   32
#define S_   200
#define D_   128
#define T_   199
#define NEGV (-1e30f)

__device__ __forceinline__ float bf2f(u16 u){
  union { u32 i; float f; } v; v.i = ((u32)u) << 16; return v.f;
}
__device__ __forceinline__ u16 f2bf(float f){
  union { float f; u32 i; } v; v.f = f;
  u32 x = v.i;
  return (u16)((x + 0x7fffu + ((x >> 16) & 1u)) >> 16);   // RNE
}
__device__ __forceinline__ float lo_(u32 u){
  union { u32 i; float f; } v; v.i = u << 16; return v.f;
}
__device__ __forceinline__ float hi_(u32 u){
  union { u32 i; float f; } v; v.i = u & 0xffff0000u; return v.f;
}
__device__ __forceinline__ u32 pk2(float x, float y){
  return ((u32)f2bf(y) << 16) | f2bf(x);
}
__device__ __forceinline__ float fast_sigmoid(float x){ return 1.f/(1.f+__expf(-x)); }
__device__ __forceinline__ float fast_tanh(float x){
  float e = __expf(2.f*x);
  return 1.f - 2.f/(e + 1.f);
}

// bool storage modes: 0=int32, 1=u8, 2=bf16, 3=f32
__device__ __forceinline__ int readBool(const void* p, int i, int m){
  if (m == 0) return ((const int*)p)[i] != 0;
  if (m == 1) return ((const unsigned char*)p)[i] != 0;
  if (m == 2) return ((const u16*)p)[i] != 0;
  return ((const u32*)p)[i] != 0;
}

__device__ __forceinline__ float dot128f(const float* __restrict__ w,
                                         const float* __restrict__ x){
  float acc = 0.f;
  const float4* wp = (const float4*)w;
  #pragma unroll 8
  for (int i = 0; i < 32; i++){
    float4 v = wp[i]; int k = 4*i;
    acc = fmaf(v.x, x[k],   acc);
    acc = fmaf(v.y, x[k+1], acc);
    acc = fmaf(v.z, x[k+2], acc);
    acc = fmaf(v.w, x[k+3], acc);
  }
  return acc;
}

// ---------------------------------------------------------------- sniffer
__global__ void k_sniff2(const u16* __restrict__ embq_raw,
                         const unsigned char* __restrict__ mask_raw,
                         int* __restrict__ flags){
  __shared__ int bad, gt1, m4, b0;
  const int tid = threadIdx.x;
  if (tid == 0){ bad = 0; gt1 = 0; m4 = 0; b0 = 0; }
  __syncthreads();
  for (int i = tid; i < 512; i += 256){
    u16 u = embq_raw[i];
    if (u){ int e = (u >> 7) & 0xFF; if (e < 0x58 || e > 0x7F) atomicAdd(&bad, 1); }
  }
  for (int i = tid; i < 1024; i += 256){
    unsigned char c = mask_raw[i];
    if (c > 1) atomicAdd(&gt1, 1);
    if (c && (i & 3)) atomicAdd(&m4, 1);
    if (c && !(i & 3)) atomicAdd(&b0, 1);
  }
  __syncthreads();
  if (tid == 0){
    flags[0] = (bad >= 16) ? 1 : 0;
    flags[1] = gt1 ? (b0 ? 2 : 3) : (m4 ? 1 : 0);
  }
}

// ---------------------------------------------------------------- convert floats -> f32
#define NCVT 23
struct CvtArgs { const void* s[NCVT]; int off[NCVT+1]; int nreal[NCVT]; };

__global__ void k_cvt(CvtArgs a, const int* __restrict__ flags, float* __restrict__ dst){
  __shared__ int f;
  if (threadIdx.x == 0) f = flags[0];
  __syncthreads();
  int gid = blockIdx.x * 256 + threadIdx.x;
  if (gid >= a.off[NCVT]) return;
  int ai = 0;
  for (int i = 1; i < NCVT; i++) if (gid >= a.off[i]) ai = i;
  int i = gid - a.off[ai];
  float v = 0.f;
  if (i < a.nreal[ai])
    v = f ? ((const float*)a.s[ai])[i] : bf2f(((const u16*)a.s[ai])[i]);
  dst[gid] = v;
}

// ---------------------------------------------------------------- K1: hop aggregation
// 2 samples/block (full lane utilization). Gather loops capped at <=8 loads
// in flight: full unroll here put ~64 loads + addresses live and spilled
// ~650 B/thread to scratch (r6: WRITE_SIZE 3.2 -> 521 MB). Keep unroll <= 4.
template<int ROWS>
__device__ __forceinline__ void agg_stage2(const float* __restrict__ tmp,
    const float* __restrict__ Wg, const float* __restrict__ bg,
    float* __restrict__ outbuf, int c)
{
  float bias = bg[c];
  float acc[ROWS];
  #pragma unroll
  for (int r = 0; r < ROWS; r++) acc[r] = bias;
  const float4* wp = (const float4*)(Wg + c*128);
  for (int i4 = 0; i4 < 32; i4++){
    float4 wv = wp[i4];
    int kk = 4*i4;
    #pragma unroll
    for (int r = 0; r < ROWS; r++){
      float4 t4 = *(const float4*)(tmp + r*128 + kk);
      acc[r] = fmaf(t4.x, wv.x, acc[r]);
      acc[r] = fmaf(t4.y, wv.y, acc[r]);
      acc[r] = fmaf(t4.z, wv.z, acc[r]);
      acc[r] = fmaf(t4.w, wv.w, acc[r]);
    }
  }
  #pragma unroll
  for (int r = 0; r < ROWS; r++)
    outbuf[r*128 + c] = fast_tanh(acc[r]);
}

__launch_bounds__(256, 4)
__global__ void k_agg(const int* __restrict__ question,
                      const int* __restrict__ q_neighbors,
                      const int* __restrict__ s_neighbors,
                      const float* __restrict__ EQ,
                      const float* __restrict__ EC,
                      const float* __restrict__ AW,
                      const float* __restrict__ AB,
                      const float* __restrict__ ALW,
                      const float* __restrict__ ALB,
                      const void* __restrict__ maskp,
                      const int* __restrict__ flags,
                      float* __restrict__ EQREC)
{
  __shared__ __align__(16) float e0[2][128];
  __shared__ __align__(16) float e1[2][512];
  __shared__ __align__(16) float e2[2][2048];
  __shared__ __align__(16) float tmpS[2][2048];
  __shared__ int nn1[2][4]; __shared__ int nn2[2][16]; __shared__ int nn3[2][64];
  const int tid  = threadIdx.x;
  const int c    = tid & 127;
  const int half = tid >> 7;
  const int bs   = blockIdx.x*2 + half;
  const int n0   = question[bs];
  float* tp = tmpS[half];

  if (c < 4) nn1[half][c] = q_neighbors[n0*4 + c];
  __syncthreads();
  if (c < 16) nn2[half][c] = s_neighbors[nn1[half][c>>2]*4 + (c&3)];
  __syncthreads();
  if (c < 64) nn3[half][c] = q_neighbors[nn2[half][c>>2]*4 + (c&3)];
  e0[half][c] = EQ[n0*128 + c];
  #pragma unroll
  for (int r = 0; r < 4; r++)  e1[half][r*128 + c] = EC[nn1[half][r]*128 + c];
  #pragma unroll 4
  for (int r = 0; r < 16; r++) e2[half][r*128 + c] = EQ[nn2[half][r]*128 + c];
  __syncthreads();

  auto fill_e0 = [&](){
    tp[c] = 0.25f*(e1[half][c] + e1[half][128+c] + e1[half][256+c] + e1[half][384+c])
          + e0[half][c];
  };
  auto fill_e1 = [&](){
    #pragma unroll
    for (int r = 0; r < 4; r++)
      tp[r*128 + c] = 0.25f*(e2[half][(4*r)*128+c]   + e2[half][(4*r+1)*128+c]
                           + e2[half][(4*r+2)*128+c] + e2[half][(4*r+3)*128+c])
                    + e1[half][r*128 + c];
  };

  // i=0: j=0,1,2
  fill_e0(); __syncthreads();
  agg_stage2<1>(tp, AW, AB, e0[half], c); __syncthreads();
  fill_e1(); __syncthreads();
  agg_stage2<4>(tp, AW + 16384, AB + 128, e1[half], c); __syncthreads();
  #pragma unroll 2
  for (int r = 0; r < 16; r++){
    float m = 0.25f*( EC[nn3[half][4*r]*128+c]   + EC[nn3[half][4*r+1]*128+c]
                    + EC[nn3[half][4*r+2]*128+c] + EC[nn3[half][4*r+3]*128+c] );
    tp[r*128 + c] = m + e2[half][r*128 + c];
  }
  __syncthreads();
  agg_stage2<16>(tp, AW + 32768, AB + 256, e2[half], c); __syncthreads();
  // i=1: j=0,1
  fill_e0(); __syncthreads();
  agg_stage2<1>(tp, AW, AB, e0[half], c); __syncthreads();
  fill_e1(); __syncthreads();
  agg_stage2<4>(tp, AW + 16384, AB + 128, e1[half], c); __syncthreads();
  // i=2: j=0
  fill_e0(); __syncthreads();
  agg_stage2<1>(tp, AW, AB, e0[half], c); __syncthreads();
  // agg = tanh(e0 @ ALW.T + ALB)
  agg_stage2<1>(e0[half], ALW, ALB, tp, c); __syncthreads();
  const int msk = readBool(maskp, bs, flags[1]);
  EQREC[bs*128 + c] = msk ? tp[c] : EQ[n0*128 + c];
}

// ---------------------------------------------------------------- K2: gi1 precompute (K=256)
__launch_bounds__(384, 1)
__global__ void k_gi1(const float* __restrict__ EQREC,
                      const int* __restrict__ response,
                      const float* __restrict__ ECOR,
                      const float* __restrict__ WIH1,
                      const float* __restrict__ BIH1,
                      float* __restrict__ GI1)
{
  const int t  = blockIdx.x;
  const int bg = blockIdx.y;
  const int tid = threadIdx.x;
  __shared__ __align__(16) float X[8][256];
  for (int o = tid; o < 2048; o += 384){
    int bb = o >> 8, k = o & 255;
    int b = bg*8 + bb;
    X[bb][k] = (k < 128) ? EQREC[(b*S_ + t)*128 + k]
                         : ECOR[response[b*S_ + t]*128 + (k - 128)];
  }
  __syncthreads();
  float bias = BIH1[tid];
  float acc[8];
  #pragma unroll
  for (int i = 0; i < 8; i++) acc[i] = bias;
  const float4* wp = (const float4*)(WIH1 + tid*256);
  #pragma unroll 2
  for (int i8 = 0; i8 < 64; i8 += 2){
    float4 v0 = wp[i8], v1 = wp[i8+1];
    float wv[8] = {v0.x,v0.y,v0.z,v0.w,v1.x,v1.y,v1.z,v1.w};
    int k0 = i8*4;
    #pragma unroll
    for (int bb = 0; bb < 8; bb++){
      #pragma unroll
      for (int kq = 0; kq < 8; kq++)
        acc[bb] = fmaf(X[bb][k0 + kq], wv[kq], acc[bb]);
    }
  }
  #pragma unroll
  for (int bb = 0; bb < 8; bb++)
    GI1[(t*32 + bg*8 + bb)*384 + tid] = acc[bb];
}

// ---------------------------------------------------------------- K2b: gi2 precompute (K=128)
__launch_bounds__(384, 1)
__global__ void k_gi2(const float* __restrict__ H1ALL,
                      const float* __restrict__ WIH2,
                      const float* __restrict__ BIH2,
                      float* __restrict__ GI2)
{
  const int t  = blockIdx.x;
  const int bg = blockIdx.y;
  const int tid = threadIdx.x;
  __shared__ __align__(16) float X[8][128];
  for (int o = tid; o < 1024; o += 384){
    int bb = o >> 7, k = o & 127;
    int b = bg*8 + bb;
    X[bb][k] = H1ALL[(t*32 + b)*128 + k];
  }
  __syncthreads();
  float bias = BIH2[tid];
  float acc[8];
  #pragma unroll
  for (int i = 0; i < 8; i++) acc[i] = bias;
  const float4* wp = (const float4*)(WIH2 + tid*128);
  #pragma unroll 2
  for (int i8 = 0; i8 < 32; i8 += 2){
    float4 v0 = wp[i8], v1 = wp[i8+1];
    float wv[8] = {v0.x,v0.y,v0.z,v0.w,v1.x,v1.y,v1.z,v1.w};
    int k0 = i8*4;
    #pragma unroll
    for (int bb = 0; bb < 8; bb++){
      #pragma unroll
      for (int kq = 0; kq < 8; kq++)
        acc[bb] = fmaf(X[bb][k0 + kq], wv[kq], acc[bb]);
    }
  }
  #pragma unroll
  for (int bb = 0; bb < 8; bb++)
    GI2[(t*32 + bg*8 + bb)*384 + tid] = acc[bb];
}

// ---------------------------------------------------------------- K3: scores + top-10
__global__ void k_topk(const int* __restrict__ question,
                       const float* __restrict__ EQ,
                       int* __restrict__ IDX)
{
  const int blk = blockIdx.x;
  const int t = blk >> 5, b = blk & 31;
  const int tid = threadIdx.x;               // 64
  __shared__ __align__(16) float qn[128];
  const int qid = question[b*S_ + t + 1];
  for (int o = tid; o < 128; o += 64) qn[o] = EQ[qid*128 + o];
  __syncthreads();
  float val[4]; int sv[4];
  #pragma unroll
  for (int i = 0; i < 4; i++){
    int s = tid + 64*i;
    sv[i] = s;
    float v = -3.0e38f;
    if (s < S_) v = (s < t) ? dot128f(EQ + question[b*S_ + s]*128, qn) : NEGV;
    val[i] = v;
  }
  for (int r = 0; r < 10; r++){
    float bv = -3.0e38f; int bi = 0x3fffffff;
    #pragma unroll
    for (int i = 0; i < 4; i++){
      if (val[i] > bv || (val[i] == bv && sv[i] < bi)){ bv = val[i]; bi = sv[i]; }
    }
    for (int off = 32; off; off >>= 1){
      float ov = __shfl_down(bv, off);
      int   oi = __shfl_down(bi, off);
      if (ov > bv || (ov == bv && oi < bi)){ bv = ov; bi = oi; }
    }
    int win = __shfl(bi, 0);
    if (tid == 0) IDX[blk*10 + r] = win;
    #pragma unroll
    for (int i = 0; i < 4; i++) if (sv[i] == win) val[i] = -3.0e38f;
  }
}

// ---------------------------------------------------------------- K4a: h1 chain
__launch_bounds__(384, 1)
__global__ void k_chain1(const float* __restrict__ GI1,
                         const float* __restrict__ WHH1,
                         const float* __restrict__ BHH1,
                         const float* __restrict__ H1I,
                         float* __restrict__ H1ALL)
{
  const int b = blockIdx.x;
  const int tid = threadIdx.x;
  __shared__ __align__(16) float h[128];
  __shared__ float gh[384];
  if (tid < 128) h[tid] = H1I[b*128 + tid];
  const float bias = BHH1[tid];
  u32 W[64];
  {
    const float4* wp = (const float4*)(WHH1 + tid*128);
    #pragma unroll
    for (int i = 0; i < 32; i++){
      float4 v = wp[i];
      W[2*i]   = pk2(v.x, v.y);
      W[2*i+1] = pk2(v.z, v.w);
    }
  }
  float irN = 0.f, izN = 0.f, innN = 0.f;
  if (tid < 128){
    const float* gp = GI1 + b*384;
    irN = gp[tid]; izN = gp[128+tid]; innN = gp[256+tid];
  }
  __syncthreads();
  for (int t = 0; t < T_; t++){
    const float ir = irN, iz = izN, inn = innN;
    if (t + 1 < T_ && tid < 128){
      const float* gp = GI1 + ((t+1)*32 + b)*384;
      irN = gp[tid]; izN = gp[128+tid]; innN = gp[256+tid];
    }
    float a = bias, ab = 0.f;
    #pragma unroll
    for (int i = 0; i < 32; i++){
      const float4 hv = *(const float4*)(h + 4*i);
      u32 u0 = W[2*i], u1 = W[2*i+1];
      a  = fmaf(lo_(u0), hv.x, a);
      ab = fmaf(hi_(u0), hv.y, ab);
      a  = fmaf(lo_(u1), hv.z, a);
      ab = fmaf(hi_(u1), hv.w, ab);
    }
    gh[tid] = a + ab;
    __syncthreads();
    if (tid < 128){
      float r = fast_sigmoid(ir + gh[tid]);
      float z = fast_sigmoid(iz + gh[128+tid]);
      float n = fast_tanh(inn + r*gh[256+tid]);
      float hn = (1.f - z)*n + z*h[tid];
      h[tid] = hn;
      H1ALL[(t*32 + b)*128 + tid] = hn;
    }
    __syncthreads();
  }
}

// ---------------------------------------------------------------- K4b: h2/g2 chain
__launch_bounds__(384, 1)
__global__ void k_chain2(const float* __restrict__ GI2,
                         const float* __restrict__ WHH2,
                         const float* __restrict__ BHH2,
                         const float* __restrict__ H2I,
                         float* __restrict__ G2)
{
  const int b = blockIdx.x;
  const int tid = threadIdx.x;
  __shared__ __align__(16) float h[128];
  __shared__ float gh[384];
  if (tid < 128) h[tid] = H2I[b*128 + tid];
  const float bias = BHH2[tid];
  u32 W[64];
  {
    const float4* wp = (const float4*)(WHH2 + tid*128);
    #pragma unroll
    for (int i = 0; i < 32; i++){
      float4 v = wp[i];
      W[2*i]   = pk2(v.x, v.y);
      W[2*i+1] = pk2(v.z, v.w);
    }
  }
  float irN = 0.f, izN = 0.f, innN = 0.f;
  if (tid < 128){
    const float* gp = GI2 + b*384;
    irN = gp[tid]; izN = gp[128+tid]; innN = gp[256+tid];
  }
  __syncthreads();
  for (int t = 0; t < T_; t++){
    const float ir = irN, iz = izN, inn = innN;
    if (t + 1 < T_ && tid < 128){
      const float* gp = GI2 + ((t+1)*32 + b)*384;
      irN = gp[tid]; izN = gp[128+tid]; innN = gp[256+tid];
    }
    float a = bias, ab = 0.f;
    #pragma unroll
    for (int i = 0; i < 32; i++){
      const float4 hv = *(const float4*)(h + 4*i);
      u32 u0 = W[2*i], u1 = W[2*i+1];
      a  = fmaf(lo_(u0), hv.x, a);
      ab = fmaf(hi_(u0), hv.y, ab);
      a  = fmaf(lo_(u1), hv.z, a);
      ab = fmaf(hi_(u1), hv.w, ab);
    }
    gh[tid] = a + ab;
    __syncthreads();
    if (tid < 128){
      float r2 = fast_sigmoid(ir + gh[tid]);
      float z2 = fast_sigmoid(iz + gh[128+tid]);
      float n2 = fast_tanh(inn + r2*gh[256+tid]);
      float g = (1.f - z2)*n2 + z2*h[tid];
      G2[(t*32 + b)*128 + tid] = g;
      if (t > 0) h[tid] = g;
    }
    __syncthreads();
  }
}

// ---------------------------------------------------------------- K5: Qp·w_q and Kp·w_k scalars
__device__ __forceinline__ float blockReduce128(float v, float* red, int tid){
  for (int off = 32; off; off >>= 1) v += __shfl_down(v, off);
  if ((tid & 63) == 0) red[tid >> 6] = v;
  __syncthreads();
  float r = red[0] + red[1];
  __syncthreads();
  return r;
}

__global__ void k_qkw(const int* __restrict__ question,
                      const int* __restrict__ qci,
                      const void* __restrict__ qcm,
                      const int* __restrict__ flags,
                      const float* __restrict__ EQ,
                      const float* __restrict__ EC,
                      const float* __restrict__ KW, const float* __restrict__ KB,
                      const float* __restrict__ QW, const float* __restrict__ QB,
                      const float* __restrict__ MW,
                      const float* __restrict__ G2,
                      float* __restrict__ QPW, float* __restrict__ KPWG)
{
  const int blk = blockIdx.x;
  const int t = blk >> 5, b = blk & 31;
  const int tid = threadIdx.x;               // 128
  __shared__ __align__(16) float row[128];
  __shared__ float red[2];
  const int qid = question[b*S_ + t + 1];
  const int bflag = flags[1];
  #pragma unroll 1
  for (int q = 0; q < 5; q++){
    float v = 0.f;
    if (q == 0) v = EQ[qid*128 + tid];
    else if (readBool(qcm, qid*4 + q - 1, bflag))
      v = EC[qci[qid*4 + q - 1]*128 + tid];
    __syncthreads();
    row[tid] = v;
    __syncthreads();
    float acc = KB[tid] + dot128f(KW + tid*128, row);
    float pv  = fast_tanh(acc) * MW[tid];              // w_q
    float s = blockReduce128(pv, red, tid);
    if (tid == 0) QPW[blk*5 + q] = s;
  }
  __syncthreads();
  row[tid] = G2[blk*128 + tid];
  __syncthreads();
  float acc = QB[tid] + dot128f(QW + tid*128, row);
  float pv  = fast_tanh(acc) * MW[128 + tid];          // w_k
  float s = blockReduce128(pv, red, tid);
  if (tid == 0) KPWG[blk] = s;
}

// ---------------------------------------------------------------- K6: predict + output
__global__ void k_pred(const int* __restrict__ question,
                       const int* __restrict__ qci, const void* __restrict__ qcm,
                       const int* __restrict__ flags,
                       const float* __restrict__ EQ, const float* __restrict__ EC,
                       const float* __restrict__ QB, const float* __restrict__ MW,
                       const float* __restrict__ MB,
                       const float* __restrict__ G2,
                       const int* __restrict__ IDX,
                       const float* __restrict__ QPW, const float* __restrict__ KPWG,
                       void* __restrict__ outp)
{
  const int blk = blockIdx.x;
  const int t = blk >> 5, b = blk & 31;
  const int tid = threadIdx.x;               // 64
  __shared__ float hist[11][132];
  __shared__ float qc[5][132];
  __shared__ float og[55];
  __shared__ float kpw[11];
  __shared__ int   idxs[10];
  __shared__ float kpw0s;
  __shared__ float pq[5];
  const int qid = question[b*S_ + t + 1];
  const int bflag = flags[1];
  if (tid < 10) idxs[tid] = IDX[blk*10 + tid];
  __syncthreads();
  for (int o = tid; o < 11*128; o += 64){
    int k = o >> 7, c = o & 127;
    float v;
    if (k == 0) v = G2[blk*128 + c];
    else { int s = idxs[k-1]; v = (s == 0) ? 0.f : G2[(s*32 + b)*128 + c]; }
    hist[k][c] = v;
  }
  for (int o = tid; o < 5*128; o += 64){
    int q = o >> 7, c = o & 127;
    float v = 0.f;
    if (q == 0) v = EQ[qid*128 + c];
    else if (readBool(qcm, qid*4 + q - 1, bflag))
      v = EC[qci[qid*4 + q - 1]*128 + c];
    qc[q][c] = v;
  }
  {
    float pv = fast_tanh(QB[tid])      * MW[128 + tid]
             + fast_tanh(QB[tid + 64]) * MW[128 + tid + 64];
    for (int off = 32; off; off >>= 1) pv += __shfl_down(pv, off);
    if (tid == 0) kpw0s = pv;
  }
  __syncthreads();
  if (tid < 55){
    int q = tid / 11, k = tid % 11;
    float acc = 0.f;
    for (int c = 0; c < 128; c++) acc = fmaf(qc[q][c], hist[k][c], acc);
    og[tid] = acc;
  }
  if (tid < 11){
    float v;
    if (tid == 0) v = KPWG[blk];
    else { int s = idxs[tid-1]; v = (s == 0) ? kpw0s : KPWG[s*32 + b]; }
    kpw[tid] = v;
  }
  __syncthreads();
  if (tid < 5){
    float qw = QPW[blk*5 + tid];
    float bb = MB[0];
    float tv[11];
    #pragma unroll
    for (int k = 0; k < 11; k++){
      int valid = (k == 0) || (idxs[k-1] < t);
      tv[k] = valid ? (qw + kpw[k] + bb) : NEGV;
    }
    float m = tv[0];
    #pragma unroll
    for (int k = 1; k < 11; k++) m = fmaxf(m, tv[k]);
    float den = 0.f, num = 0.f;
    #pragma unroll
    for (int k = 0; k < 11; k++){
      float e = __expf(tv[k] - m);
      den += e;
      num = fmaf(e, og[tid*11 + k], num);
    }
    pq[tid] = num / den;
  }
  __syncthreads();
  if (tid == 0){
    float p = pq[0] + pq[1] + pq[2] + pq[3] + pq[4];
    int col = (t == 0) ? 0 : (t + 1);
    if (flags[0]){
      ((float*)outp)[b*S_ + col] = p;
      if (t == 0) ((float*)outp)[b*S_ + 1] = 0.f;
    } else {
      ((u16*)outp)[b*S_ + col] = f2bf(p);
      if (t == 0) ((u16*)outp)[b*S_ + 1] = (u16)0;
    }
  }
}

// ---------------------------------------------------------------- launcher
extern "C" void kernel_launch(void* const* d_in, const int* in_sizes, int n_in,
                              void* d_out, int out_size, void* d_ws, size_t ws_size,
                              hipStream_t stream)
{
  (void)in_sizes; (void)n_in; (void)out_size; (void)ws_size;
  const int* question      = (const int*)d_in[0];
  const int* response      = (const int*)d_in[1];
  const void* maskp        = d_in[2];
  const int* q_neighbors   = (const int*)d_in[3];
  const int* s_neighbors   = (const int*)d_in[4];
  const int* q_concept_idx = (const int*)d_in[5];
  const void* q_concept_mask = d_in[6];

  static const int CN[NCVT] = {2560000,256000,256,98304,49152,384,384,49152,49152,
                               384,384,49152,384,16384,128,16384,128,16384,128,
                               256,1,4096,4096};
  CvtArgs ca;
  int off = 0;
  for (int i = 0; i < NCVT; i++){
    ca.s[i] = d_in[7 + i];
    ca.nreal[i] = CN[i];
    ca.off[i] = off;
    off += (CN[i] + 3) & ~3;
  }
  ca.off[NCVT] = off;
  const int total = off;

  char* ws = (char*)d_ws;
  size_t wo = 0;
  auto alloc = [&](size_t bytes) -> void* {
    void* p = ws + wo;
    wo = (wo + bytes + 255) & ~(size_t)255;
    return p;
  };
  int*   flags = (int*)  alloc(16);
  float* CVT   = (float*)alloc((size_t)total * 4);
  float* EQREC = (float*)alloc((size_t)B_*S_*D_*4);
  float* GI1   = (float*)alloc((size_t)T_*B_*384*4);
  float* GI2A  = (float*)alloc((size_t)T_*B_*384*4);
  float* H1ALL = (float*)alloc((size_t)T_*B_*D_*4);
  float* G2    = (float*)alloc((size_t)T_*B_*D_*4);
  int*   IDX   = (int*)  alloc((size_t)T_*B_*10*4);
  float* QPW   = (float*)alloc((size_t)T_*B_*5*4);
  float* KPWG  = (float*)alloc((size_t)T_*B_*4);

  const float* EQ   = CVT + ca.off[0];
  const float* EC   = CVT + ca.off[1];
  const float* ECOR = CVT + ca.off[2];
  const float* WIH1 = CVT + ca.off[3];
  const float* WHH1 = CVT + ca.off[4];
  const float* BIH1 = CVT + ca.off[5];
  const float* BHH1 = CVT + ca.off[6];
  const float* WIH2 = CVT + ca.off[7];
  const float* WHH2 = CVT + ca.off[8];
  const float* BIH2 = CVT + ca.off[9];
  const float* BHH2 = CVT + ca.off[10];
  const float* AW   = CVT + ca.off[11];
  const float* AB   = CVT + ca.off[12];
  const float* ALW  = CVT + ca.off[13];
  const float* ALB  = CVT + ca.off[14];
  const float* QW   = CVT + ca.off[15];
  const float* QB   = CVT + ca.off[16];
  const float* KW   = CVT + ca.off[17];
  const float* KB   = CVT + ca.off[18];
  const float* MW   = CVT + ca.off[19];
  const float* MB   = CVT + ca.off[20];
  const float* H1I  = CVT + ca.off[21];
  const float* H2I  = CVT + ca.off[22];

  k_sniff2<<<1, 256, 0, stream>>>((const u16*)d_in[7], (const unsigned char*)maskp, flags);
  k_cvt<<<(total + 255)/256, 256, 0, stream>>>(ca, flags, CVT);
  k_agg<<<B_*S_/2, 256, 0, stream>>>(question, q_neighbors, s_neighbors, EQ, EC,
                                     AW, AB, ALW, ALB, maskp, flags, EQREC);
  k_gi1<<<dim3(T_, 4), 384, 0, stream>>>(EQREC, response, ECOR, WIH1, BIH1, GI1);
  k_topk<<<T_*B_, 64, 0, stream>>>(question, EQ, IDX);
  k_chain1<<<B_, 384, 0, stream>>>(GI1, WHH1, BHH1, H1I, H1ALL);
  k_gi2<<<dim3(T_, 4), 384, 0, stream>>>(H1ALL, WIH2, BIH2, GI2A);
  k_chain2<<<B_, 384, 0, stream>>>(GI2A, WHH2, BHH2, H2I, G2);
  k_qkw<<<T_*B_, 128, 0, stream>>>(question, q_concept_idx, q_concept_mask, flags,
                                   EQ, EC, KW, KB, QW, QB, MW, G2, QPW, KPWG);
  k_pred<<<T_*B_, 64, 0, stream>>>(question, q_concept_idx, q_concept_mask, flags,
                                   EQ, EC, QB, MW, MB, G2, IDX, QPW, KPWG, d_out);
}

// Round 8
// 1282.785 us; speedup vs baseline: 1.2067x; 1.2067x over previous
//
#include <hip/hip_runtime.h>
#include <math.h>

typedef unsigned short u16;
typedef unsigned int   u32;

#define B_   32
#define S_   200
#define D_   128
#define T_   199
#define NEGV (-1e30f)

__device__ __forceinline__ float bf2f(u16 u){
  union { u32 i; float f; } v; v.i = ((u32)u) << 16; return v.f;
}
__device__ __forceinline__ u16 f2bf(float f){
  union { float f; u32 i; } v; v.f = f;
  u32 x = v.i;
  return (u16)((x + 0x7fffu + ((x >> 16) & 1u)) >> 16);   // RNE
}
__device__ __forceinline__ float lo_(u32 u){
  union { u32 i; float f; } v; v.i = u << 16; return v.f;
}
__device__ __forceinline__ float hi_(u32 u){
  union { u32 i; float f; } v; v.i = u & 0xffff0000u; return v.f;
}
__device__ __forceinline__ u32 pk2(float x, float y){
  return ((u32)f2bf(y) << 16) | f2bf(x);
}
__device__ __forceinline__ float fast_sigmoid(float x){ return 1.f/(1.f+__expf(-x)); }
__device__ __forceinline__ float fast_tanh(float x){
  float e = __expf(2.f*x);
  return 1.f - 2.f/(e + 1.f);
}

// bool storage modes: 0=int32, 1=u8, 2=bf16, 3=f32
__device__ __forceinline__ int readBool(const void* p, int i, int m){
  if (m == 0) return ((const int*)p)[i] != 0;
  if (m == 1) return ((const unsigned char*)p)[i] != 0;
  if (m == 2) return ((const u16*)p)[i] != 0;
  return ((const u32*)p)[i] != 0;
}

__device__ __forceinline__ float dot128f(const float* __restrict__ w,
                                         const float* __restrict__ x){
  float acc = 0.f;
  const float4* wp = (const float4*)w;
  #pragma unroll 8
  for (int i = 0; i < 32; i++){
    float4 v = wp[i]; int k = 4*i;
    acc = fmaf(v.x, x[k],   acc);
    acc = fmaf(v.y, x[k+1], acc);
    acc = fmaf(v.z, x[k+2], acc);
    acc = fmaf(v.w, x[k+3], acc);
  }
  return acc;
}

// ---------------------------------------------------------------- sniffer
__global__ void k_sniff2(const u16* __restrict__ embq_raw,
                         const unsigned char* __restrict__ mask_raw,
                         int* __restrict__ flags){
  __shared__ int bad, gt1, m4, b0;
  const int tid = threadIdx.x;
  if (tid == 0){ bad = 0; gt1 = 0; m4 = 0; b0 = 0; }
  __syncthreads();
  for (int i = tid; i < 512; i += 256){
    u16 u = embq_raw[i];
    if (u){ int e = (u >> 7) & 0xFF; if (e < 0x58 || e > 0x7F) atomicAdd(&bad, 1); }
  }
  for (int i = tid; i < 1024; i += 256){
    unsigned char c = mask_raw[i];
    if (c > 1) atomicAdd(&gt1, 1);
    if (c && (i & 3)) atomicAdd(&m4, 1);
    if (c && !(i & 3)) atomicAdd(&b0, 1);
  }
  __syncthreads();
  if (tid == 0){
    flags[0] = (bad >= 16) ? 1 : 0;
    flags[1] = gt1 ? (b0 ? 2 : 3) : (m4 ? 1 : 0);
  }
}

// ---------------------------------------------------------------- convert floats -> f32
#define NCVT 23
struct CvtArgs { const void* s[NCVT]; int off[NCVT+1]; int nreal[NCVT]; };

__global__ void k_cvt(CvtArgs a, const int* __restrict__ flags, float* __restrict__ dst){
  __shared__ int f;
  if (threadIdx.x == 0) f = flags[0];
  __syncthreads();
  int gid = blockIdx.x * 256 + threadIdx.x;
  if (gid >= a.off[NCVT]) return;
  int ai = 0;
  for (int i = 1; i < NCVT; i++) if (gid >= a.off[i]) ai = i;
  int i = gid - a.off[ai];
  float v = 0.f;
  if (i < a.nreal[ai])
    v = f ? ((const float*)a.s[ai])[i] : bf2f(((const u16*)a.s[ai])[i]);
  dst[gid] = v;
}

// ---------------------------------------------------------------- K1: hop aggregation
// 2 samples/block (full lane utilization).
// SPILL LESSON (r6/r7): the 32-trip weight loop MUST keep `#pragma unroll 4`.
// Without it LLVM fully unrolls, hoists all 32 float4 weight loads (~128
// VGPRs) over the 16-acc FMA chain, and spills ~648 B/thread
// (3200 blk x 256 thr x 648 B = the measured 518 MB WRITE_SIZE).
template<int ROWS>
__device__ __forceinline__ void agg_stage2(const float* __restrict__ tmp,
    const float* __restrict__ Wg, const float* __restrict__ bg,
    float* __restrict__ outbuf, int c)
{
  float bias = bg[c];
  float acc[ROWS];
  #pragma unroll
  for (int r = 0; r < ROWS; r++) acc[r] = bias;
  const float4* wp = (const float4*)(Wg + c*128);
  #pragma unroll 4
  for (int i4 = 0; i4 < 32; i4++){
    float4 wv = wp[i4];
    int kk = 4*i4;
    #pragma unroll
    for (int r = 0; r < ROWS; r++){
      float4 t4 = *(const float4*)(tmp + r*128 + kk);
      acc[r] = fmaf(t4.x, wv.x, acc[r]);
      acc[r] = fmaf(t4.y, wv.y, acc[r]);
      acc[r] = fmaf(t4.z, wv.z, acc[r]);
      acc[r] = fmaf(t4.w, wv.w, acc[r]);
    }
  }
  #pragma unroll
  for (int r = 0; r < ROWS; r++)
    outbuf[r*128 + c] = fast_tanh(acc[r]);
}

__launch_bounds__(256, 4)
__global__ void k_agg(const int* __restrict__ question,
                      const int* __restrict__ q_neighbors,
                      const int* __restrict__ s_neighbors,
                      const float* __restrict__ EQ,
                      const float* __restrict__ EC,
                      const float* __restrict__ AW,
                      const float* __restrict__ AB,
                      const float* __restrict__ ALW,
                      const float* __restrict__ ALB,
                      const void* __restrict__ maskp,
                      const int* __restrict__ flags,
                      float* __restrict__ EQREC)
{
  __shared__ __align__(16) float e0[2][128];
  __shared__ __align__(16) float e1[2][512];
  __shared__ __align__(16) float e2[2][2048];
  __shared__ __align__(16) float tmpS[2][2048];
  __shared__ int nn1[2][4]; __shared__ int nn2[2][16]; __shared__ int nn3[2][64];
  const int tid  = threadIdx.x;
  const int c    = tid & 127;
  const int half = tid >> 7;
  const int bs   = blockIdx.x*2 + half;
  const int n0   = question[bs];
  float* tp = tmpS[half];

  if (c < 4) nn1[half][c] = q_neighbors[n0*4 + c];
  __syncthreads();
  if (c < 16) nn2[half][c] = s_neighbors[nn1[half][c>>2]*4 + (c&3)];
  __syncthreads();
  if (c < 64) nn3[half][c] = q_neighbors[nn2[half][c>>2]*4 + (c&3)];
  e0[half][c] = EQ[n0*128 + c];
  #pragma unroll
  for (int r = 0; r < 4; r++)  e1[half][r*128 + c] = EC[nn1[half][r]*128 + c];
  #pragma unroll 4
  for (int r = 0; r < 16; r++) e2[half][r*128 + c] = EQ[nn2[half][r]*128 + c];
  __syncthreads();

  auto fill_e0 = [&](){
    tp[c] = 0.25f*(e1[half][c] + e1[half][128+c] + e1[half][256+c] + e1[half][384+c])
          + e0[half][c];
  };
  auto fill_e1 = [&](){
    #pragma unroll
    for (int r = 0; r < 4; r++)
      tp[r*128 + c] = 0.25f*(e2[half][(4*r)*128+c]   + e2[half][(4*r+1)*128+c]
                           + e2[half][(4*r+2)*128+c] + e2[half][(4*r+3)*128+c])
                    + e1[half][r*128 + c];
  };

  // i=0: j=0,1,2
  fill_e0(); __syncthreads();
  agg_stage2<1>(tp, AW, AB, e0[half], c); __syncthreads();
  fill_e1(); __syncthreads();
  agg_stage2<4>(tp, AW + 16384, AB + 128, e1[half], c); __syncthreads();
  #pragma unroll 2
  for (int r = 0; r < 16; r++){
    float m = 0.25f*( EC[nn3[half][4*r]*128+c]   + EC[nn3[half][4*r+1]*128+c]
                    + EC[nn3[half][4*r+2]*128+c] + EC[nn3[half][4*r+3]*128+c] );
    tp[r*128 + c] = m + e2[half][r*128 + c];
  }
  __syncthreads();
  agg_stage2<16>(tp, AW + 32768, AB + 256, e2[half], c); __syncthreads();
  // i=1: j=0,1
  fill_e0(); __syncthreads();
  agg_stage2<1>(tp, AW, AB, e0[half], c); __syncthreads();
  fill_e1(); __syncthreads();
  agg_stage2<4>(tp, AW + 16384, AB + 128, e1[half], c); __syncthreads();
  // i=2: j=0
  fill_e0(); __syncthreads();
  agg_stage2<1>(tp, AW, AB, e0[half], c); __syncthreads();
  // agg = tanh(e0 @ ALW.T + ALB)
  agg_stage2<1>(e0[half], ALW, ALB, tp, c); __syncthreads();
  const int msk = readBool(maskp, bs, flags[1]);
  EQREC[bs*128 + c] = msk ? tp[c] : EQ[n0*128 + c];
}

// ---------------------------------------------------------------- K2: gi1 precompute (K=256)
__launch_bounds__(384, 1)
__global__ void k_gi1(const float* __restrict__ EQREC,
                      const int* __restrict__ response,
                      const float* __restrict__ ECOR,
                      const float* __restrict__ WIH1,
                      const float* __restrict__ BIH1,
                      float* __restrict__ GI1)
{
  const int t  = blockIdx.x;
  const int bg = blockIdx.y;
  const int tid = threadIdx.x;
  __shared__ __align__(16) float X[8][256];
  for (int o = tid; o < 2048; o += 384){
    int bb = o >> 8, k = o & 255;
    int b = bg*8 + bb;
    X[bb][k] = (k < 128) ? EQREC[(b*S_ + t)*128 + k]
                         : ECOR[response[b*S_ + t]*128 + (k - 128)];
  }
  __syncthreads();
  float bias = BIH1[tid];
  float acc[8];
  #pragma unroll
  for (int i = 0; i < 8; i++) acc[i] = bias;
  const float4* wp = (const float4*)(WIH1 + tid*256);
  #pragma unroll 2
  for (int i8 = 0; i8 < 64; i8 += 2){
    float4 v0 = wp[i8], v1 = wp[i8+1];
    float wv[8] = {v0.x,v0.y,v0.z,v0.w,v1.x,v1.y,v1.z,v1.w};
    int k0 = i8*4;
    #pragma unroll
    for (int bb = 0; bb < 8; bb++){
      #pragma unroll
      for (int kq = 0; kq < 8; kq++)
        acc[bb] = fmaf(X[bb][k0 + kq], wv[kq], acc[bb]);
    }
  }
  #pragma unroll
  for (int bb = 0; bb < 8; bb++)
    GI1[(t*32 + bg*8 + bb)*384 + tid] = acc[bb];
}

// ---------------------------------------------------------------- K2b: gi2 precompute (K=128)
__launch_bounds__(384, 1)
__global__ void k_gi2(const float* __restrict__ H1ALL,
                      const float* __restrict__ WIH2,
                      const float* __restrict__ BIH2,
                      float* __restrict__ GI2)
{
  const int t  = blockIdx.x;
  const int bg = blockIdx.y;
  const int tid = threadIdx.x;
  __shared__ __align__(16) float X[8][128];
  for (int o = tid; o < 1024; o += 384){
    int bb = o >> 7, k = o & 127;
    int b = bg*8 + bb;
    X[bb][k] = H1ALL[(t*32 + b)*128 + k];
  }
  __syncthreads();
  float bias = BIH2[tid];
  float acc[8];
  #pragma unroll
  for (int i = 0; i < 8; i++) acc[i] = bias;
  const float4* wp = (const float4*)(WIH2 + tid*128);
  #pragma unroll 2
  for (int i8 = 0; i8 < 32; i8 += 2){
    float4 v0 = wp[i8], v1 = wp[i8+1];
    float wv[8] = {v0.x,v0.y,v0.z,v0.w,v1.x,v1.y,v1.z,v1.w};
    int k0 = i8*4;
    #pragma unroll
    for (int bb = 0; bb < 8; bb++){
      #pragma unroll
      for (int kq = 0; kq < 8; kq++)
        acc[bb] = fmaf(X[bb][k0 + kq], wv[kq], acc[bb]);
    }
  }
  #pragma unroll
  for (int bb = 0; bb < 8; bb++)
    GI2[(t*32 + bg*8 + bb)*384 + tid] = acc[bb];
}

// ---------------------------------------------------------------- K3: scores + top-10
__global__ void k_topk(const int* __restrict__ question,
                       const float* __restrict__ EQ,
                       int* __restrict__ IDX)
{
  const int blk = blockIdx.x;
  const int t = blk >> 5, b = blk & 31;
  const int tid = threadIdx.x;               // 64
  __shared__ __align__(16) float qn[128];
  const int qid = question[b*S_ + t + 1];
  for (int o = tid; o < 128; o += 64) qn[o] = EQ[qid*128 + o];
  __syncthreads();
  float val[4]; int sv[4];
  #pragma unroll
  for (int i = 0; i < 4; i++){
    int s = tid + 64*i;
    sv[i] = s;
    float v = -3.0e38f;
    if (s < S_) v = (s < t) ? dot128f(EQ + question[b*S_ + s]*128, qn) : NEGV;
    val[i] = v;
  }
  for (int r = 0; r < 10; r++){
    float bv = -3.0e38f; int bi = 0x3fffffff;
    #pragma unroll
    for (int i = 0; i < 4; i++){
      if (val[i] > bv || (val[i] == bv && sv[i] < bi)){ bv = val[i]; bi = sv[i]; }
    }
    for (int off = 32; off; off >>= 1){
      float ov = __shfl_down(bv, off);
      int   oi = __shfl_down(bi, off);
      if (ov > bv || (ov == bv && oi < bi)){ bv = ov; bi = oi; }
    }
    int win = __shfl(bi, 0);
    if (tid == 0) IDX[blk*10 + r] = win;
    #pragma unroll
    for (int i = 0; i < 4; i++) if (sv[i] == win) val[i] = -3.0e38f;
  }
}

// ---------------------------------------------------------------- K4a: h1 chain
__launch_bounds__(384, 1)
__global__ void k_chain1(const float* __restrict__ GI1,
                         const float* __restrict__ WHH1,
                         const float* __restrict__ BHH1,
                         const float* __restrict__ H1I,
                         float* __restrict__ H1ALL)
{
  const int b = blockIdx.x;
  const int tid = threadIdx.x;
  __shared__ __align__(16) float h[128];
  __shared__ float gh[384];
  if (tid < 128) h[tid] = H1I[b*128 + tid];
  const float bias = BHH1[tid];
  u32 W[64];
  {
    const float4* wp = (const float4*)(WHH1 + tid*128);
    #pragma unroll
    for (int i = 0; i < 32; i++){
      float4 v = wp[i];
      W[2*i]   = pk2(v.x, v.y);
      W[2*i+1] = pk2(v.z, v.w);
    }
  }
  float irN = 0.f, izN = 0.f, innN = 0.f;
  if (tid < 128){
    const float* gp = GI1 + b*384;
    irN = gp[tid]; izN = gp[128+tid]; innN = gp[256+tid];
  }
  __syncthreads();
  for (int t = 0; t < T_; t++){
    const float ir = irN, iz = izN, inn = innN;
    if (t + 1 < T_ && tid < 128){
      const float* gp = GI1 + ((t+1)*32 + b)*384;
      irN = gp[tid]; izN = gp[128+tid]; innN = gp[256+tid];
    }
    float a = bias, ab = 0.f;
    #pragma unroll
    for (int i = 0; i < 32; i++){
      const float4 hv = *(const float4*)(h + 4*i);
      u32 u0 = W[2*i], u1 = W[2*i+1];
      a  = fmaf(lo_(u0), hv.x, a);
      ab = fmaf(hi_(u0), hv.y, ab);
      a  = fmaf(lo_(u1), hv.z, a);
      ab = fmaf(hi_(u1), hv.w, ab);
    }
    gh[tid] = a + ab;
    __syncthreads();
    if (tid < 128){
      float r = fast_sigmoid(ir + gh[tid]);
      float z = fast_sigmoid(iz + gh[128+tid]);
      float n = fast_tanh(inn + r*gh[256+tid]);
      float hn = (1.f - z)*n + z*h[tid];
      h[tid] = hn;
      H1ALL[(t*32 + b)*128 + tid] = hn;
    }
    __syncthreads();
  }
}

// ---------------------------------------------------------------- K4b: h2/g2 chain
__launch_bounds__(384, 1)
__global__ void k_chain2(const float* __restrict__ GI2,
                         const float* __restrict__ WHH2,
                         const float* __restrict__ BHH2,
                         const float* __restrict__ H2I,
                         float* __restrict__ G2)
{
  const int b = blockIdx.x;
  const int tid = threadIdx.x;
  __shared__ __align__(16) float h[128];
  __shared__ float gh[384];
  if (tid < 128) h[tid] = H2I[b*128 + tid];
  const float bias = BHH2[tid];
  u32 W[64];
  {
    const float4* wp = (const float4*)(WHH2 + tid*128);
    #pragma unroll
    for (int i = 0; i < 32; i++){
      float4 v = wp[i];
      W[2*i]   = pk2(v.x, v.y);
      W[2*i+1] = pk2(v.z, v.w);
    }
  }
  float irN = 0.f, izN = 0.f, innN = 0.f;
  if (tid < 128){
    const float* gp = GI2 + b*384;
    irN = gp[tid]; izN = gp[128+tid]; innN = gp[256+tid];
  }
  __syncthreads();
  for (int t = 0; t < T_; t++){
    const float ir = irN, iz = izN, inn = innN;
    if (t + 1 < T_ && tid < 128){
      const float* gp = GI2 + ((t+1)*32 + b)*384;
      irN = gp[tid]; izN = gp[128+tid]; innN = gp[256+tid];
    }
    float a = bias, ab = 0.f;
    #pragma unroll
    for (int i = 0; i < 32; i++){
      const float4 hv = *(const float4*)(h + 4*i);
      u32 u0 = W[2*i], u1 = W[2*i+1];
      a  = fmaf(lo_(u0), hv.x, a);
      ab = fmaf(hi_(u0), hv.y, ab);
      a  = fmaf(lo_(u1), hv.z, a);
      ab = fmaf(hi_(u1), hv.w, ab);
    }
    gh[tid] = a + ab;
    __syncthreads();
    if (tid < 128){
      float r2 = fast_sigmoid(ir + gh[tid]);
      float z2 = fast_sigmoid(iz + gh[128+tid]);
      float n2 = fast_tanh(inn + r2*gh[256+tid]);
      float g = (1.f - z2)*n2 + z2*h[tid];
      G2[(t*32 + b)*128 + tid] = g;
      if (t > 0) h[tid] = g;
    }
    __syncthreads();
  }
}

// ---------------------------------------------------------------- K5: Qp·w_q and Kp·w_k scalars
__device__ __forceinline__ float blockReduce128(float v, float* red, int tid){
  for (int off = 32; off; off >>= 1) v += __shfl_down(v, off);
  if ((tid & 63) == 0) red[tid >> 6] = v;
  __syncthreads();
  float r = red[0] + red[1];
  __syncthreads();
  return r;
}

__global__ void k_qkw(const int* __restrict__ question,
                      const int* __restrict__ qci,
                      const void* __restrict__ qcm,
                      const int* __restrict__ flags,
                      const float* __restrict__ EQ,
                      const float* __restrict__ EC,
                      const float* __restrict__ KW, const float* __restrict__ KB,
                      const float* __restrict__ QW, const float* __restrict__ QB,
                      const float* __restrict__ MW,
                      const float* __restrict__ G2,
                      float* __restrict__ QPW, float* __restrict__ KPWG)
{
  const int blk = blockIdx.x;
  const int t = blk >> 5, b = blk & 31;
  const int tid = threadIdx.x;               // 128
  __shared__ __align__(16) float row[128];
  __shared__ float red[2];
  const int qid = question[b*S_ + t + 1];
  const int bflag = flags[1];
  #pragma unroll 1
  for (int q = 0; q < 5; q++){
    float v = 0.f;
    if (q == 0) v = EQ[qid*128 + tid];
    else if (readBool(qcm, qid*4 + q - 1, bflag))
      v = EC[qci[qid*4 + q - 1]*128 + tid];
    __syncthreads();
    row[tid] = v;
    __syncthreads();
    float acc = KB[tid] + dot128f(KW + tid*128, row);
    float pv  = fast_tanh(acc) * MW[tid];              // w_q
    float s = blockReduce128(pv, red, tid);
    if (tid == 0) QPW[blk*5 + q] = s;
  }
  __syncthreads();
  row[tid] = G2[blk*128 + tid];
  __syncthreads();
  float acc = QB[tid] + dot128f(QW + tid*128, row);
  float pv  = fast_tanh(acc) * MW[128 + tid];          // w_k
  float s = blockReduce128(pv, red, tid);
  if (tid == 0) KPWG[blk] = s;
}

// ---------------------------------------------------------------- K6: predict + output
__global__ void k_pred(const int* __restrict__ question,
                       const int* __restrict__ qci, const void* __restrict__ qcm,
                       const int* __restrict__ flags,
                       const float* __restrict__ EQ, const float* __restrict__ EC,
                       const float* __restrict__ QB, const float* __restrict__ MW,
                       const float* __restrict__ MB,
                       const float* __restrict__ G2,
                       const int* __restrict__ IDX,
                       const float* __restrict__ QPW, const float* __restrict__ KPWG,
                       void* __restrict__ outp)
{
  const int blk = blockIdx.x;
  const int t = blk >> 5, b = blk & 31;
  const int tid = threadIdx.x;               // 64
  __shared__ float hist[11][132];
  __shared__ float qc[5][132];
  __shared__ float og[55];
  __shared__ float kpw[11];
  __shared__ int   idxs[10];
  __shared__ float kpw0s;
  __shared__ float pq[5];
  const int qid = question[b*S_ + t + 1];
  const int bflag = flags[1];
  if (tid < 10) idxs[tid] = IDX[blk*10 + tid];
  __syncthreads();
  for (int o = tid; o < 11*128; o += 64){
    int k = o >> 7, c = o & 127;
    float v;
    if (k == 0) v = G2[blk*128 + c];
    else { int s = idxs[k-1]; v = (s == 0) ? 0.f : G2[(s*32 + b)*128 + c]; }
    hist[k][c] = v;
  }
  for (int o = tid; o < 5*128; o += 64){
    int q = o >> 7, c = o & 127;
    float v = 0.f;
    if (q == 0) v = EQ[qid*128 + c];
    else if (readBool(qcm, qid*4 + q - 1, bflag))
      v = EC[qci[qid*4 + q - 1]*128 + c];
    qc[q][c] = v;
  }
  {
    float pv = fast_tanh(QB[tid])      * MW[128 + tid]
             + fast_tanh(QB[tid + 64]) * MW[128 + tid + 64];
    for (int off = 32; off; off >>= 1) pv += __shfl_down(pv, off);
    if (tid == 0) kpw0s = pv;
  }
  __syncthreads();
  if (tid < 55){
    int q = tid / 11, k = tid % 11;
    float acc = 0.f;
    for (int c = 0; c < 128; c++) acc = fmaf(qc[q][c], hist[k][c], acc);
    og[tid] = acc;
  }
  if (tid < 11){
    float v;
    if (tid == 0) v = KPWG[blk];
    else { int s = idxs[tid-1]; v = (s == 0) ? kpw0s : KPWG[s*32 + b]; }
    kpw[tid] = v;
  }
  __syncthreads();
  if (tid < 5){
    float qw = QPW[blk*5 + tid];
    float bb = MB[0];
    float tv[11];
    #pragma unroll
    for (int k = 0; k < 11; k++){
      int valid = (k == 0) || (idxs[k-1] < t);
      tv[k] = valid ? (qw + kpw[k] + bb) : NEGV;
    }
    float m = tv[0];
    #pragma unroll
    for (int k = 1; k < 11; k++) m = fmaxf(m, tv[k]);
    float den = 0.f, num = 0.f;
    #pragma unroll
    for (int k = 0; k < 11; k++){
      float e = __expf(tv[k] - m);
      den += e;
      num = fmaf(e, og[tid*11 + k], num);
    }
    pq[tid] = num / den;
  }
  __syncthreads();
  if (tid == 0){
    float p = pq[0] + pq[1] + pq[2] + pq[3] + pq[4];
    int col = (t == 0) ? 0 : (t + 1);
    if (flags[0]){
      ((float*)outp)[b*S_ + col] = p;
      if (t == 0) ((float*)outp)[b*S_ + 1] = 0.f;
    } else {
      ((u16*)outp)[b*S_ + col] = f2bf(p);
      if (t == 0) ((u16*)outp)[b*S_ + 1] = (u16)0;
    }
  }
}

// ---------------------------------------------------------------- launcher
extern "C" void kernel_launch(void* const* d_in, const int* in_sizes, int n_in,
                              void* d_out, int out_size, void* d_ws, size_t ws_size,
                              hipStream_t stream)
{
  (void)in_sizes; (void)n_in; (void)out_size; (void)ws_size;
  const int* question      = (const int*)d_in[0];
  const int* response      = (const int*)d_in[1];
  const void* maskp        = d_in[2];
  const int* q_neighbors   = (const int*)d_in[3];
  const int* s_neighbors   = (const int*)d_in[4];
  const int* q_concept_idx = (const int*)d_in[5];
  const void* q_concept_mask = d_in[6];

  static const int CN[NCVT] = {2560000,256000,256,98304,49152,384,384,49152,49152,
                               384,384,49152,384,16384,128,16384,128,16384,128,
                               256,1,4096,4096};
  CvtArgs ca;
  int off = 0;
  for (int i = 0; i < NCVT; i++){
    ca.s[i] = d_in[7 + i];
    ca.nreal[i] = CN[i];
    ca.off[i] = off;
    off += (CN[i] + 3) & ~3;
  }
  ca.off[NCVT] = off;
  const int total = off;

  char* ws = (char*)d_ws;
  size_t wo = 0;
  auto alloc = [&](size_t bytes) -> void* {
    void* p = ws + wo;
    wo = (wo + bytes + 255) & ~(size_t)255;
    return p;
  };
  int*   flags = (int*)  alloc(16);
  float* CVT   = (float*)alloc((size_t)total * 4);
  float* EQREC = (float*)alloc((size_t)B_*S_*D_*4);
  float* GI1   = (float*)alloc((size_t)T_*B_*384*4);
  float* GI2A  = (float*)alloc((size_t)T_*B_*384*4);
  float* H1ALL = (float*)alloc((size_t)T_*B_*D_*4);
  float* G2    = (float*)alloc((size_t)T_*B_*D_*4);
  int*   IDX   = (int*)  alloc((size_t)T_*B_*10*4);
  float* QPW   = (float*)alloc((size_t)T_*B_*5*4);
  float* KPWG  = (float*)alloc((size_t)T_*B_*4);

  const float* EQ   = CVT + ca.off[0];
  const float* EC   = CVT + ca.off[1];
  const float* ECOR = CVT + ca.off[2];
  const float* WIH1 = CVT + ca.off[3];
  const float* WHH1 = CVT + ca.off[4];
  const float* BIH1 = CVT + ca.off[5];
  const float* BHH1 = CVT + ca.off[6];
  const float* WIH2 = CVT + ca.off[7];
  const float* WHH2 = CVT + ca.off[8];
  const float* BIH2 = CVT + ca.off[9];
  const float* BHH2 = CVT + ca.off[10];
  const float* AW   = CVT + ca.off[11];
  const float* AB   = CVT + ca.off[12];
  const float* ALW  = CVT + ca.off[13];
  const float* ALB  = CVT + ca.off[14];
  const float* QW   = CVT + ca.off[15];
  const float* QB   = CVT + ca.off[16];
  const float* KW   = CVT + ca.off[17];
  const float* KB   = CVT + ca.off[18];
  const float* MW   = CVT + ca.off[19];
  const float* MB   = CVT + ca.off[20];
  const float* H1I  = CVT + ca.off[21];
  const float* H2I  = CVT + ca.off[22];

  k_sniff2<<<1, 256, 0, stream>>>((const u16*)d_in[7], (const unsigned char*)maskp, flags);
  k_cvt<<<(total + 255)/256, 256, 0, stream>>>(ca, flags, CVT);
  k_agg<<<B_*S_/2, 256, 0, stream>>>(question, q_neighbors, s_neighbors, EQ, EC,
                                     AW, AB, ALW, ALB, maskp, flags, EQREC);
  k_gi1<<<dim3(T_, 4), 384, 0, stream>>>(EQREC, response, ECOR, WIH1, BIH1, GI1);
  k_topk<<<T_*B_, 64, 0, stream>>>(question, EQ, IDX);
  k_chain1<<<B_, 384, 0, stream>>>(GI1, WHH1, BHH1, H1I, H1ALL);
  k_gi2<<<dim3(T_, 4), 384, 0, stream>>>(H1ALL, WIH2, BIH2, GI2A);
  k_chain2<<<B_, 384, 0, stream>>>(GI2A, WHH2, BHH2, H2I, G2);
  k_qkw<<<T_*B_, 128, 0, stream>>>(question, q_concept_idx, q_concept_mask, flags,
                                   EQ, EC, KW, KB, QW, QB, MW, G2, QPW, KPWG);
  k_pred<<<T_*B_, 64, 0, stream>>>(question, q_concept_idx, q_concept_mask, flags,
                                   EQ, EC, QB, MW, MB, G2, IDX, QPW, KPWG, d_out);
}

// Round 9
// 1036.381 us; speedup vs baseline: 1.4936x; 1.2378x over previous
//
#include <hip/hip_runtime.h>
#include <math.h>

typedef unsigned short u16;
typedef unsigned int   u32;
typedef __attribute__((ext_vector_type(2))) _Float16 half2_t;

#define B_   32
#define S_   200
#define D_   128
#define T_   199
#define NEGV (-1e30f)

__device__ __forceinline__ float bf2f(u16 u){
  union { u32 i; float f; } v; v.i = ((u32)u) << 16; return v.f;
}
__device__ __forceinline__ u16 f2bf(float f){
  union { float f; u32 i; } v; v.f = f;
  u32 x = v.i;
  return (u16)((x + 0x7fffu + ((x >> 16) & 1u)) >> 16);   // RNE
}
__device__ __forceinline__ u16 f2h(float x){
  union { _Float16 h; u16 u; } v; v.h = (_Float16)x; return v.u;
}
__device__ __forceinline__ float h2f(u16 u){
  union { u16 u; _Float16 h; } v; v.u = u; return (float)v.h;
}
// 2 MACs/instr: f32 += f16x2 . f16x2  (v_dot2_f32_f16)
__device__ __forceinline__ float dot2f(u32 w, u32 h, float acc){
#if __has_builtin(__builtin_amdgcn_fdot2)
  union { u32 u; half2_t h2; } a, b;
  a.u = w; b.u = h;
  return __builtin_amdgcn_fdot2(a.h2, b.h2, acc, false);
#else
  union { u32 u; _Float16 f[2]; } a, b;
  a.u = w; b.u = h;
  acc = fmaf((float)a.f[0], (float)b.f[0], acc);
  return fmaf((float)a.f[1], (float)b.f[1], acc);
#endif
}
__device__ __forceinline__ float fast_sigmoid(float x){ return 1.f/(1.f+__expf(-x)); }
__device__ __forceinline__ float fast_tanh(float x){
  float e = __expf(2.f*x);
  return 1.f - 2.f/(e + 1.f);
}

// bool storage modes: 0=int32, 1=u8, 2=bf16, 3=f32
__device__ __forceinline__ int readBool(const void* p, int i, int m){
  if (m == 0) return ((const int*)p)[i] != 0;
  if (m == 1) return ((const unsigned char*)p)[i] != 0;
  if (m == 2) return ((const u16*)p)[i] != 0;
  return ((const u32*)p)[i] != 0;
}

__device__ __forceinline__ float dot128f(const float* __restrict__ w,
                                         const float* __restrict__ x){
  float acc = 0.f;
  const float4* wp = (const float4*)w;
  #pragma unroll 8
  for (int i = 0; i < 32; i++){
    float4 v = wp[i]; int k = 4*i;
    acc = fmaf(v.x, x[k],   acc);
    acc = fmaf(v.y, x[k+1], acc);
    acc = fmaf(v.z, x[k+2], acc);
    acc = fmaf(v.w, x[k+3], acc);
  }
  return acc;
}

// ---------------------------------------------------------------- sniffer
__global__ void k_sniff2(const u16* __restrict__ embq_raw,
                         const unsigned char* __restrict__ mask_raw,
                         int* __restrict__ flags){
  __shared__ int bad, gt1, m4, b0;
  const int tid = threadIdx.x;
  if (tid == 0){ bad = 0; gt1 = 0; m4 = 0; b0 = 0; }
  __syncthreads();
  for (int i = tid; i < 512; i += 256){
    u16 u = embq_raw[i];
    if (u){ int e = (u >> 7) & 0xFF; if (e < 0x58 || e > 0x7F) atomicAdd(&bad, 1); }
  }
  for (int i = tid; i < 1024; i += 256){
    unsigned char c = mask_raw[i];
    if (c > 1) atomicAdd(&gt1, 1);
    if (c && (i & 3)) atomicAdd(&m4, 1);
    if (c && !(i & 3)) atomicAdd(&b0, 1);
  }
  __syncthreads();
  if (tid == 0){
    flags[0] = (bad >= 16) ? 1 : 0;
    flags[1] = gt1 ? (b0 ? 2 : 3) : (m4 ? 1 : 0);
  }
}

// ---------------------------------------------------------------- convert floats -> f32
#define NCVT 23
struct CvtArgs { const void* s[NCVT]; int off[NCVT+1]; int nreal[NCVT]; };

__global__ void k_cvt(CvtArgs a, const int* __restrict__ flags, float* __restrict__ dst){
  __shared__ int f;
  if (threadIdx.x == 0) f = flags[0];
  __syncthreads();
  int gid = blockIdx.x * 256 + threadIdx.x;
  if (gid >= a.off[NCVT]) return;
  int ai = 0;
  for (int i = 1; i < NCVT; i++) if (gid >= a.off[i]) ai = i;
  int i = gid - a.off[ai];
  float v = 0.f;
  if (i < a.nreal[ai])
    v = f ? ((const float*)a.s[ai])[i] : bf2f(((const u16*)a.s[ai])[i]);
  dst[gid] = v;
}

// ---------------------------------------------------------------- prep: f32 -> packed f16 weights
__global__ void k_prep(const float* __restrict__ WHH1, const float* __restrict__ WHH2,
                       const float* __restrict__ AW,   const float* __restrict__ ALW,
                       u16* __restrict__ WHH1h, u16* __restrict__ WHH2h,
                       u16* __restrict__ AWh,   u16* __restrict__ ALWh){
  int gid = blockIdx.x*256 + threadIdx.x;
  if (gid < 49152){
    WHH1h[gid] = f2h(WHH1[gid]);
    WHH2h[gid] = f2h(WHH2[gid]);
    AWh[gid]   = f2h(AW[gid]);
  }
  if (gid < 16384) ALWh[gid] = f2h(ALW[gid]);
}

// ---------------------------------------------------------------- K1: hop aggregation (f16 dot2)
// 2 samples/block; all e/tmp tiles in LDS as f16 (19.3 KB -> 8 blocks/CU by
// LDS). Matvec = v_dot2_f32_f16 (2 MAC/instr). Weight stream f16 uint4.
// SPILL RULES (r3/r6): weight loop unroll <= 4; launch_bounds (256,4) keeps
// the VGPR cap at 128.
template<int ROWS>
__device__ __forceinline__ void agg_stage_h(const u16* __restrict__ tmph,
    const u16* __restrict__ Wh, const float* __restrict__ bg,
    u16* __restrict__ outh, int c)
{
  float bias = bg[c];
  float acc[ROWS];
  #pragma unroll
  for (int r = 0; r < ROWS; r++) acc[r] = bias;
  const uint4* wp = (const uint4*)(Wh + c*128);   // 16 x (8 f16)
  #pragma unroll 4
  for (int i = 0; i < 16; i++){
    uint4 wv = wp[i];
    #pragma unroll
    for (int r = 0; r < ROWS; r++){
      uint4 hv = *(const uint4*)(tmph + r*128 + i*8);   // broadcast read
      acc[r] = dot2f(wv.x, hv.x, acc[r]);
      acc[r] = dot2f(wv.y, hv.y, acc[r]);
      acc[r] = dot2f(wv.z, hv.z, acc[r]);
      acc[r] = dot2f(wv.w, hv.w, acc[r]);
    }
  }
  #pragma unroll
  for (int r = 0; r < ROWS; r++)
    outh[r*128 + c] = f2h(fast_tanh(acc[r]));
}

__launch_bounds__(256, 4)
__global__ void k_agg(const int* __restrict__ question,
                      const int* __restrict__ q_neighbors,
                      const int* __restrict__ s_neighbors,
                      const float* __restrict__ EQ,
                      const float* __restrict__ EC,
                      const u16* __restrict__ AWh,
                      const float* __restrict__ AB,
                      const u16* __restrict__ ALWh,
                      const float* __restrict__ ALB,
                      const void* __restrict__ maskp,
                      const int* __restrict__ flags,
                      float* __restrict__ EQREC)
{
  __shared__ __align__(16) u16 e0h[2][128];
  __shared__ __align__(16) u16 e1h[2][512];
  __shared__ __align__(16) u16 e2h[2][2048];
  __shared__ __align__(16) u16 tmph[2][2048];
  __shared__ int nn1[2][4]; __shared__ int nn2[2][16]; __shared__ int nn3[2][64];
  const int tid  = threadIdx.x;
  const int c    = tid & 127;
  const int half = tid >> 7;
  const int bs   = blockIdx.x*2 + half;
  const int n0   = question[bs];
  u16* tp = tmph[half];

  if (c < 4) nn1[half][c] = q_neighbors[n0*4 + c];
  __syncthreads();
  if (c < 16) nn2[half][c] = s_neighbors[nn1[half][c>>2]*4 + (c&3)];
  __syncthreads();
  if (c < 64) nn3[half][c] = q_neighbors[nn2[half][c>>2]*4 + (c&3)];
  e0h[half][c] = f2h(EQ[n0*128 + c]);
  #pragma unroll
  for (int r = 0; r < 4; r++)  e1h[half][r*128 + c] = f2h(EC[nn1[half][r]*128 + c]);
  #pragma unroll 4
  for (int r = 0; r < 16; r++) e2h[half][r*128 + c] = f2h(EQ[nn2[half][r]*128 + c]);
  __syncthreads();

  auto fill_e0 = [&](){
    float v = 0.25f*(h2f(e1h[half][c]) + h2f(e1h[half][128+c])
                   + h2f(e1h[half][256+c]) + h2f(e1h[half][384+c]))
            + h2f(e0h[half][c]);
    tp[c] = f2h(v);
  };
  auto fill_e1 = [&](){
    #pragma unroll
    for (int r = 0; r < 4; r++){
      float v = 0.25f*(h2f(e2h[half][(4*r)*128+c])   + h2f(e2h[half][(4*r+1)*128+c])
                     + h2f(e2h[half][(4*r+2)*128+c]) + h2f(e2h[half][(4*r+3)*128+c]))
              + h2f(e1h[half][r*128 + c]);
      tp[r*128 + c] = f2h(v);
    }
  };

  // i=0: j=0,1,2
  fill_e0(); __syncthreads();
  agg_stage_h<1>(tp, AWh, AB, e0h[half], c); __syncthreads();
  fill_e1(); __syncthreads();
  agg_stage_h<4>(tp, AWh + 16384, AB + 128, e1h[half], c); __syncthreads();
  #pragma unroll 2
  for (int r = 0; r < 16; r++){
    float m = 0.25f*( EC[nn3[half][4*r]*128+c]   + EC[nn3[half][4*r+1]*128+c]
                    + EC[nn3[half][4*r+2]*128+c] + EC[nn3[half][4*r+3]*128+c] );
    tp[r*128 + c] = f2h(m + h2f(e2h[half][r*128 + c]));
  }
  __syncthreads();
  agg_stage_h<16>(tp, AWh + 32768, AB + 256, e2h[half], c); __syncthreads();
  // i=1: j=0,1
  fill_e0(); __syncthreads();
  agg_stage_h<1>(tp, AWh, AB, e0h[half], c); __syncthreads();
  fill_e1(); __syncthreads();
  agg_stage_h<4>(tp, AWh + 16384, AB + 128, e1h[half], c); __syncthreads();
  // i=2: j=0
  fill_e0(); __syncthreads();
  agg_stage_h<1>(tp, AWh, AB, e0h[half], c); __syncthreads();
  // agg = tanh(e0 @ ALW.T + ALB)
  agg_stage_h<1>(e0h[half], ALWh, ALB, tp, c); __syncthreads();
  const int msk = readBool(maskp, bs, flags[1]);
  EQREC[bs*128 + c] = msk ? h2f(tp[c]) : EQ[n0*128 + c];
}

// ---------------------------------------------------------------- K2: gi1 precompute (K=256)
__launch_bounds__(384, 1)
__global__ void k_gi1(const float* __restrict__ EQREC,
                      const int* __restrict__ response,
                      const float* __restrict__ ECOR,
                      const float* __restrict__ WIH1,
                      const float* __restrict__ BIH1,
                      float* __restrict__ GI1)
{
  const int t  = blockIdx.x;
  const int bg = blockIdx.y;
  const int tid = threadIdx.x;
  __shared__ __align__(16) float X[8][256];
  for (int o = tid; o < 2048; o += 384){
    int bb = o >> 8, k = o & 255;
    int b = bg*8 + bb;
    X[bb][k] = (k < 128) ? EQREC[(b*S_ + t)*128 + k]
                         : ECOR[response[b*S_ + t]*128 + (k - 128)];
  }
  __syncthreads();
  float bias = BIH1[tid];
  float acc[8];
  #pragma unroll
  for (int i = 0; i < 8; i++) acc[i] = bias;
  const float4* wp = (const float4*)(WIH1 + tid*256);
  #pragma unroll 2
  for (int i8 = 0; i8 < 64; i8 += 2){
    float4 v0 = wp[i8], v1 = wp[i8+1];
    float wv[8] = {v0.x,v0.y,v0.z,v0.w,v1.x,v1.y,v1.z,v1.w};
    int k0 = i8*4;
    #pragma unroll
    for (int bb = 0; bb < 8; bb++){
      #pragma unroll
      for (int kq = 0; kq < 8; kq++)
        acc[bb] = fmaf(X[bb][k0 + kq], wv[kq], acc[bb]);
    }
  }
  #pragma unroll
  for (int bb = 0; bb < 8; bb++)
    GI1[(t*32 + bg*8 + bb)*384 + tid] = acc[bb];
}

// ---------------------------------------------------------------- K2b: gi2 precompute (K=128)
__launch_bounds__(384, 1)
__global__ void k_gi2(const float* __restrict__ H1ALL,
                      const float* __restrict__ WIH2,
                      const float* __restrict__ BIH2,
                      float* __restrict__ GI2)
{
  const int t  = blockIdx.x;
  const int bg = blockIdx.y;
  const int tid = threadIdx.x;
  __shared__ __align__(16) float X[8][128];
  for (int o = tid; o < 1024; o += 384){
    int bb = o >> 7, k = o & 127;
    int b = bg*8 + bb;
    X[bb][k] = H1ALL[(t*32 + b)*128 + k];
  }
  __syncthreads();
  float bias = BIH2[tid];
  float acc[8];
  #pragma unroll
  for (int i = 0; i < 8; i++) acc[i] = bias;
  const float4* wp = (const float4*)(WIH2 + tid*128);
  #pragma unroll 2
  for (int i8 = 0; i8 < 32; i8 += 2){
    float4 v0 = wp[i8], v1 = wp[i8+1];
    float wv[8] = {v0.x,v0.y,v0.z,v0.w,v1.x,v1.y,v1.z,v1.w};
    int k0 = i8*4;
    #pragma unroll
    for (int bb = 0; bb < 8; bb++){
      #pragma unroll
      for (int kq = 0; kq < 8; kq++)
        acc[bb] = fmaf(X[bb][k0 + kq], wv[kq], acc[bb]);
    }
  }
  #pragma unroll
  for (int bb = 0; bb < 8; bb++)
    GI2[(t*32 + bg*8 + bb)*384 + tid] = acc[bb];
}

// ---------------------------------------------------------------- K3: scores + top-10
__global__ void k_topk(const int* __restrict__ question,
                       const float* __restrict__ EQ,
                       int* __restrict__ IDX)
{
  const int blk = blockIdx.x;
  const int t = blk >> 5, b = blk & 31;
  const int tid = threadIdx.x;               // 64
  __shared__ __align__(16) float qn[128];
  const int qid = question[b*S_ + t + 1];
  for (int o = tid; o < 128; o += 64) qn[o] = EQ[qid*128 + o];
  __syncthreads();
  float val[4]; int sv[4];
  #pragma unroll
  for (int i = 0; i < 4; i++){
    int s = tid + 64*i;
    sv[i] = s;
    float v = -3.0e38f;
    if (s < S_) v = (s < t) ? dot128f(EQ + question[b*S_ + s]*128, qn) : NEGV;
    val[i] = v;
  }
  for (int r = 0; r < 10; r++){
    float bv = -3.0e38f; int bi = 0x3fffffff;
    #pragma unroll
    for (int i = 0; i < 4; i++){
      if (val[i] > bv || (val[i] == bv && sv[i] < bi)){ bv = val[i]; bi = sv[i]; }
    }
    for (int off = 32; off; off >>= 1){
      float ov = __shfl_down(bv, off);
      int   oi = __shfl_down(bi, off);
      if (ov > bv || (ov == bv && oi < bi)){ bv = ov; bi = oi; }
    }
    int win = __shfl(bi, 0);
    if (tid == 0) IDX[blk*10 + r] = win;
    #pragma unroll
    for (int i = 0; i < 4; i++) if (sv[i] == win) val[i] = -3.0e38f;
  }
}

// ---------------------------------------------------------------- K4a: h1 chain (f16 dot2)
// Weights: 64 u32 of packed f16 in VGPRs (same budget as the proven bf16
// version). h mirrored in LDS as f16 for the matvec; f32 copy kept for gates.
__launch_bounds__(384, 1)
__global__ void k_chain1(const float* __restrict__ GI1,
                         const u16* __restrict__ WHH1h,
                         const float* __restrict__ BHH1,
                         const float* __restrict__ H1I,
                         float* __restrict__ H1ALL)
{
  const int b = blockIdx.x;
  const int tid = threadIdx.x;
  __shared__ __align__(16) float h[128];
  __shared__ __align__(16) u16 hh[128];
  __shared__ float gh[384];
  if (tid < 128){ float v = H1I[b*128 + tid]; h[tid] = v; hh[tid] = f2h(v); }
  const float bias = BHH1[tid];
  u32 W[64];
  {
    const uint4* wp = (const uint4*)(WHH1h + tid*128);
    #pragma unroll
    for (int i = 0; i < 16; i++){
      uint4 v = wp[i];
      W[4*i] = v.x; W[4*i+1] = v.y; W[4*i+2] = v.z; W[4*i+3] = v.w;
    }
  }
  float irN = 0.f, izN = 0.f, innN = 0.f;
  if (tid < 128){
    const float* gp = GI1 + b*384;
    irN = gp[tid]; izN = gp[128+tid]; innN = gp[256+tid];
  }
  __syncthreads();
  for (int t = 0; t < T_; t++){
    const float ir = irN, iz = izN, inn = innN;
    if (t + 1 < T_ && tid < 128){
      const float* gp = GI1 + ((t+1)*32 + b)*384;
      irN = gp[tid]; izN = gp[128+tid]; innN = gp[256+tid];
    }
    float a = bias, ab = 0.f;
    #pragma unroll
    for (int i = 0; i < 16; i++){
      uint4 hv = *(const uint4*)(hh + i*8);
      a  = dot2f(W[4*i],   hv.x, a);
      ab = dot2f(W[4*i+1], hv.y, ab);
      a  = dot2f(W[4*i+2], hv.z, a);
      ab = dot2f(W[4*i+3], hv.w, ab);
    }
    gh[tid] = a + ab;
    __syncthreads();
    if (tid < 128){
      float r = fast_sigmoid(ir + gh[tid]);
      float z = fast_sigmoid(iz + gh[128+tid]);
      float n = fast_tanh(inn + r*gh[256+tid]);
      float hn = (1.f - z)*n + z*h[tid];
      h[tid] = hn;
      hh[tid] = f2h(hn);
      H1ALL[(t*32 + b)*128 + tid] = hn;
    }
    __syncthreads();
  }
}

// ---------------------------------------------------------------- K4b: h2/g2 chain (f16 dot2)
__launch_bounds__(384, 1)
__global__ void k_chain2(const float* __restrict__ GI2,
                         const u16* __restrict__ WHH2h,
                         const float* __restrict__ BHH2,
                         const float* __restrict__ H2I,
                         float* __restrict__ G2)
{
  const int b = blockIdx.x;
  const int tid = threadIdx.x;
  __shared__ __align__(16) float h[128];
  __shared__ __align__(16) u16 hh[128];
  __shared__ float gh[384];
  if (tid < 128){ float v = H2I[b*128 + tid]; h[tid] = v; hh[tid] = f2h(v); }
  const float bias = BHH2[tid];
  u32 W[64];
  {
    const uint4* wp = (const uint4*)(WHH2h + tid*128);
    #pragma unroll
    for (int i = 0; i < 16; i++){
      uint4 v = wp[i];
      W[4*i] = v.x; W[4*i+1] = v.y; W[4*i+2] = v.z; W[4*i+3] = v.w;
    }
  }
  float irN = 0.f, izN = 0.f, innN = 0.f;
  if (tid < 128){
    const float* gp = GI2 + b*384;
    irN = gp[tid]; izN = gp[128+tid]; innN = gp[256+tid];
  }
  __syncthreads();
  for (int t = 0; t < T_; t++){
    const float ir = irN, iz = izN, inn = innN;
    if (t + 1 < T_ && tid < 128){
      const float* gp = GI2 + ((t+1)*32 + b)*384;
      irN = gp[tid]; izN = gp[128+tid]; innN = gp[256+tid];
    }
    float a = bias, ab = 0.f;
    #pragma unroll
    for (int i = 0; i < 16; i++){
      uint4 hv = *(const uint4*)(hh + i*8);
      a  = dot2f(W[4*i],   hv.x, a);
      ab = dot2f(W[4*i+1], hv.y, ab);
      a  = dot2f(W[4*i+2], hv.z, a);
      ab = dot2f(W[4*i+3], hv.w, ab);
    }
    gh[tid] = a + ab;
    __syncthreads();
    if (tid < 128){
      float r2 = fast_sigmoid(ir + gh[tid]);
      float z2 = fast_sigmoid(iz + gh[128+tid]);
      float n2 = fast_tanh(inn + r2*gh[256+tid]);
      float g = (1.f - z2)*n2 + z2*h[tid];
      G2[(t*32 + b)*128 + tid] = g;
      if (t > 0){ h[tid] = g; hh[tid] = f2h(g); }
    }
    __syncthreads();
  }
}

// ---------------------------------------------------------------- K5: Qp·w_q and Kp·w_k scalars
__device__ __forceinline__ float blockReduce128(float v, float* red, int tid){
  for (int off = 32; off; off >>= 1) v += __shfl_down(v, off);
  if ((tid & 63) == 0) red[tid >> 6] = v;
  __syncthreads();
  float r = red[0] + red[1];
  __syncthreads();
  return r;
}

__global__ void k_qkw(const int* __restrict__ question,
                      const int* __restrict__ qci,
                      const void* __restrict__ qcm,
                      const int* __restrict__ flags,
                      const float* __restrict__ EQ,
                      const float* __restrict__ EC,
                      const float* __restrict__ KW, const float* __restrict__ KB,
                      const float* __restrict__ QW, const float* __restrict__ QB,
                      const float* __restrict__ MW,
                      const float* __restrict__ G2,
                      float* __restrict__ QPW, float* __restrict__ KPWG)
{
  const int blk = blockIdx.x;
  const int t = blk >> 5, b = blk & 31;
  const int tid = threadIdx.x;               // 128
  __shared__ __align__(16) float row[128];
  __shared__ float red[2];
  const int qid = question[b*S_ + t + 1];
  const int bflag = flags[1];
  #pragma unroll 1
  for (int q = 0; q < 5; q++){
    float v = 0.f;
    if (q == 0) v = EQ[qid*128 + tid];
    else if (readBool(qcm, qid*4 + q - 1, bflag))
      v = EC[qci[qid*4 + q - 1]*128 + tid];
    __syncthreads();
    row[tid] = v;
    __syncthreads();
    float acc = KB[tid] + dot128f(KW + tid*128, row);
    float pv  = fast_tanh(acc) * MW[tid];              // w_q
    float s = blockReduce128(pv, red, tid);
    if (tid == 0) QPW[blk*5 + q] = s;
  }
  __syncthreads();
  row[tid] = G2[blk*128 + tid];
  __syncthreads();
  float acc = QB[tid] + dot128f(QW + tid*128, row);
  float pv  = fast_tanh(acc) * MW[128 + tid];          // w_k
  float s = blockReduce128(pv, red, tid);
  if (tid == 0) KPWG[blk] = s;
}

// ---------------------------------------------------------------- K6: predict + output
__global__ void k_pred(const int* __restrict__ question,
                       const int* __restrict__ qci, const void* __restrict__ qcm,
                       const int* __restrict__ flags,
                       const float* __restrict__ EQ, const float* __restrict__ EC,
                       const float* __restrict__ QB, const float* __restrict__ MW,
                       const float* __restrict__ MB,
                       const float* __restrict__ G2,
                       const int* __restrict__ IDX,
                       const float* __restrict__ QPW, const float* __restrict__ KPWG,
                       void* __restrict__ outp)
{
  const int blk = blockIdx.x;
  const int t = blk >> 5, b = blk & 31;
  const int tid = threadIdx.x;               // 64
  __shared__ float hist[11][132];
  __shared__ float qc[5][132];
  __shared__ float og[55];
  __shared__ float kpw[11];
  __shared__ int   idxs[10];
  __shared__ float kpw0s;
  __shared__ float pq[5];
  const int qid = question[b*S_ + t + 1];
  const int bflag = flags[1];
  if (tid < 10) idxs[tid] = IDX[blk*10 + tid];
  __syncthreads();
  for (int o = tid; o < 11*128; o += 64){
    int k = o >> 7, c = o & 127;
    float v;
    if (k == 0) v = G2[blk*128 + c];
    else { int s = idxs[k-1]; v = (s == 0) ? 0.f : G2[(s*32 + b)*128 + c]; }
    hist[k][c] = v;
  }
  for (int o = tid; o < 5*128; o += 64){
    int q = o >> 7, c = o & 127;
    float v = 0.f;
    if (q == 0) v = EQ[qid*128 + c];
    else if (readBool(qcm, qid*4 + q - 1, bflag))
      v = EC[qci[qid*4 + q - 1]*128 + c];
    qc[q][c] = v;
  }
  {
    float pv = fast_tanh(QB[tid])      * MW[128 + tid]
             + fast_tanh(QB[tid + 64]) * MW[128 + tid + 64];
    for (int off = 32; off; off >>= 1) pv += __shfl_down(pv, off);
    if (tid == 0) kpw0s = pv;
  }
  __syncthreads();
  if (tid < 55){
    int q = tid / 11, k = tid % 11;
    float acc = 0.f;
    for (int c = 0; c < 128; c++) acc = fmaf(qc[q][c], hist[k][c], acc);
    og[tid] = acc;
  }
  if (tid < 11){
    float v;
    if (tid == 0) v = KPWG[blk];
    else { int s = idxs[tid-1]; v = (s == 0) ? kpw0s : KPWG[s*32 + b]; }
    kpw[tid] = v;
  }
  __syncthreads();
  if (tid < 5){
    float qw = QPW[blk*5 + tid];
    float bb = MB[0];
    float tv[11];
    #pragma unroll
    for (int k = 0; k < 11; k++){
      int valid = (k == 0) || (idxs[k-1] < t);
      tv[k] = valid ? (qw + kpw[k] + bb) : NEGV;
    }
    float m = tv[0];
    #pragma unroll
    for (int k = 1; k < 11; k++) m = fmaxf(m, tv[k]);
    float den = 0.f, num = 0.f;
    #pragma unroll
    for (int k = 0; k < 11; k++){
      float e = __expf(tv[k] - m);
      den += e;
      num = fmaf(e, og[tid*11 + k], num);
    }
    pq[tid] = num / den;
  }
  __syncthreads();
  if (tid == 0){
    float p = pq[0] + pq[1] + pq[2] + pq[3] + pq[4];
    int col = (t == 0) ? 0 : (t + 1);
    if (flags[0]){
      ((float*)outp)[b*S_ + col] = p;
      if (t == 0) ((float*)outp)[b*S_ + 1] = 0.f;
    } else {
      ((u16*)outp)[b*S_ + col] = f2bf(p);
      if (t == 0) ((u16*)outp)[b*S_ + 1] = (u16)0;
    }
  }
}

// ---------------------------------------------------------------- launcher
extern "C" void kernel_launch(void* const* d_in, const int* in_sizes, int n_in,
                              void* d_out, int out_size, void* d_ws, size_t ws_size,
                              hipStream_t stream)
{
  (void)in_sizes; (void)n_in; (void)out_size; (void)ws_size;
  const int* question      = (const int*)d_in[0];
  const int* response      = (const int*)d_in[1];
  const void* maskp        = d_in[2];
  const int* q_neighbors   = (const int*)d_in[3];
  const int* s_neighbors   = (const int*)d_in[4];
  const int* q_concept_idx = (const int*)d_in[5];
  const void* q_concept_mask = d_in[6];

  static const int CN[NCVT] = {2560000,256000,256,98304,49152,384,384,49152,49152,
                               384,384,49152,384,16384,128,16384,128,16384,128,
                               256,1,4096,4096};
  CvtArgs ca;
  int off = 0;
  for (int i = 0; i < NCVT; i++){
    ca.s[i] = d_in[7 + i];
    ca.nreal[i] = CN[i];
    ca.off[i] = off;
    off += (CN[i] + 3) & ~3;
  }
  ca.off[NCVT] = off;
  const int total = off;

  char* ws = (char*)d_ws;
  size_t wo = 0;
  auto alloc = [&](size_t bytes) -> void* {
    void* p = ws + wo;
    wo = (wo + bytes + 255) & ~(size_t)255;
    return p;
  };
  int*   flags = (int*)  alloc(16);
  float* CVT   = (float*)alloc((size_t)total * 4);
  float* EQREC = (float*)alloc((size_t)B_*S_*D_*4);
  float* GI1   = (float*)alloc((size_t)T_*B_*384*4);
  float* GI2A  = (float*)alloc((size_t)T_*B_*384*4);
  float* H1ALL = (float*)alloc((size_t)T_*B_*D_*4);
  float* G2    = (float*)alloc((size_t)T_*B_*D_*4);
  int*   IDX   = (int*)  alloc((size_t)T_*B_*10*4);
  float* QPW   = (float*)alloc((size_t)T_*B_*5*4);
  float* KPWG  = (float*)alloc((size_t)T_*B_*4);
  u16*   WHH1h = (u16*)  alloc(49152*2);
  u16*   WHH2h = (u16*)  alloc(49152*2);
  u16*   AWh   = (u16*)  alloc(49152*2);
  u16*   ALWh  = (u16*)  alloc(16384*2);

  const float* EQ   = CVT + ca.off[0];
  const float* EC   = CVT + ca.off[1];
  const float* ECOR = CVT + ca.off[2];
  const float* WIH1 = CVT + ca.off[3];
  const float* WHH1 = CVT + ca.off[4];
  const float* BIH1 = CVT + ca.off[5];
  const float* BHH1 = CVT + ca.off[6];
  const float* WIH2 = CVT + ca.off[7];
  const float* WHH2 = CVT + ca.off[8];
  const float* BIH2 = CVT + ca.off[9];
  const float* BHH2 = CVT + ca.off[10];
  const float* AW   = CVT + ca.off[11];
  const float* AB   = CVT + ca.off[12];
  const float* ALW  = CVT + ca.off[13];
  const float* ALB  = CVT + ca.off[14];
  const float* QW   = CVT + ca.off[15];
  const float* QB   = CVT + ca.off[16];
  const float* KW   = CVT + ca.off[17];
  const float* KB   = CVT + ca.off[18];
  const float* MW   = CVT + ca.off[19];
  const float* MB   = CVT + ca.off[20];
  const float* H1I  = CVT + ca.off[21];
  const float* H2I  = CVT + ca.off[22];

  k_sniff2<<<1, 256, 0, stream>>>((const u16*)d_in[7], (const unsigned char*)maskp, flags);
  k_cvt<<<(total + 255)/256, 256, 0, stream>>>(ca, flags, CVT);
  k_prep<<<192, 256, 0, stream>>>(WHH1, WHH2, AW, ALW, WHH1h, WHH2h, AWh, ALWh);
  k_agg<<<B_*S_/2, 256, 0, stream>>>(question, q_neighbors, s_neighbors, EQ, EC,
                                     AWh, AB, ALWh, ALB, maskp, flags, EQREC);
  k_gi1<<<dim3(T_, 4), 384, 0, stream>>>(EQREC, response, ECOR, WIH1, BIH1, GI1);
  k_topk<<<T_*B_, 64, 0, stream>>>(question, EQ, IDX);
  k_chain1<<<B_, 384, 0, stream>>>(GI1, WHH1h, BHH1, H1I, H1ALL);
  k_gi2<<<dim3(T_, 4), 384, 0, stream>>>(H1ALL, WIH2, BIH2, GI2A);
  k_chain2<<<B_, 384, 0, stream>>>(GI2A, WHH2h, BHH2, H2I, G2);
  k_qkw<<<T_*B_, 128, 0, stream>>>(question, q_concept_idx, q_concept_mask, flags,
                                   EQ, EC, KW, KB, QW, QB, MW, G2, QPW, KPWG);
  k_pred<<<T_*B_, 64, 0, stream>>>(question, q_concept_idx, q_concept_mask, flags,
                                   EQ, EC, QB, MW, MB, G2, IDX, QPW, KPWG, d_out);
}

// Round 10
// 775.664 us; speedup vs baseline: 1.9957x; 1.3361x over previous
//
#include <hip/hip_runtime.h>
#include <math.h>

typedef unsigned short u16;
typedef unsigned int   u32;
typedef __attribute__((ext_vector_type(2))) _Float16 half2_t;

#define B_   32
#define S_   200
#define D_   128
#define T_   199
#define NEGV (-1e30f)

__device__ __forceinline__ float bf2f(u16 u){
  union { u32 i; float f; } v; v.i = ((u32)u) << 16; return v.f;
}
__device__ __forceinline__ u16 f2bf(float f){
  union { float f; u32 i; } v; v.f = f;
  u32 x = v.i;
  return (u16)((x + 0x7fffu + ((x >> 16) & 1u)) >> 16);   // RNE
}
__device__ __forceinline__ u16 f2h(float x){
  union { _Float16 h; u16 u; } v; v.h = (_Float16)x; return v.u;
}
__device__ __forceinline__ float h2f(u16 u){
  union { u16 u; _Float16 h; } v; v.u = u; return (float)v.h;
}
// 2 MACs/instr: f32 += f16x2 . f16x2  (v_dot2_f32_f16)
__device__ __forceinline__ float dot2f(u32 w, u32 h, float acc){
#if __has_builtin(__builtin_amdgcn_fdot2)
  union { u32 u; half2_t h2; } a, b;
  a.u = w; b.u = h;
  return __builtin_amdgcn_fdot2(a.h2, b.h2, acc, false);
#else
  union { u32 u; _Float16 f[2]; } a, b;
  a.u = w; b.u = h;
  acc = fmaf((float)a.f[0], (float)b.f[0], acc);
  return fmaf((float)a.f[1], (float)b.f[1], acc);
#endif
}
__device__ __forceinline__ float fast_sigmoid(float x){ return 1.f/(1.f+__expf(-x)); }
__device__ __forceinline__ float fast_tanh(float x){
  float e = __expf(2.f*x);
  return 1.f - 2.f/(e + 1.f);
}

// bool storage modes: 0=int32, 1=u8, 2=bf16, 3=f32
__device__ __forceinline__ int readBool(const void* p, int i, int m){
  if (m == 0) return ((const int*)p)[i] != 0;
  if (m == 1) return ((const unsigned char*)p)[i] != 0;
  if (m == 2) return ((const u16*)p)[i] != 0;
  return ((const u32*)p)[i] != 0;
}

__device__ __forceinline__ float dot128f(const float* __restrict__ w,
                                         const float* __restrict__ x){
  float acc = 0.f;
  const float4* wp = (const float4*)w;
  #pragma unroll 8
  for (int i = 0; i < 32; i++){
    float4 v = wp[i]; int k = 4*i;
    acc = fmaf(v.x, x[k],   acc);
    acc = fmaf(v.y, x[k+1], acc);
    acc = fmaf(v.z, x[k+2], acc);
    acc = fmaf(v.w, x[k+3], acc);
  }
  return acc;
}

// ---------------------------------------------------------------- sniffer
__global__ void k_sniff2(const u16* __restrict__ embq_raw,
                         const unsigned char* __restrict__ mask_raw,
                         int* __restrict__ flags){
  __shared__ int bad, gt1, m4, b0;
  const int tid = threadIdx.x;
  if (tid == 0){ bad = 0; gt1 = 0; m4 = 0; b0 = 0; }
  __syncthreads();
  for (int i = tid; i < 512; i += 256){
    u16 u = embq_raw[i];
    if (u){ int e = (u >> 7) & 0xFF; if (e < 0x58 || e > 0x7F) atomicAdd(&bad, 1); }
  }
  for (int i = tid; i < 1024; i += 256){
    unsigned char c = mask_raw[i];
    if (c > 1) atomicAdd(&gt1, 1);
    if (c && (i & 3)) atomicAdd(&m4, 1);
    if (c && !(i & 3)) atomicAdd(&b0, 1);
  }
  __syncthreads();
  if (tid == 0){
    flags[0] = (bad >= 16) ? 1 : 0;
    flags[1] = gt1 ? (b0 ? 2 : 3) : (m4 ? 1 : 0);
  }
}

// ---------------------------------------------------------------- convert floats -> f32
#define NCVT 23
struct CvtArgs { const void* s[NCVT]; int off[NCVT+1]; int nreal[NCVT]; };

__global__ void k_cvt(CvtArgs a, const int* __restrict__ flags, float* __restrict__ dst){
  __shared__ int f;
  if (threadIdx.x == 0) f = flags[0];
  __syncthreads();
  int gid = blockIdx.x * 256 + threadIdx.x;
  if (gid >= a.off[NCVT]) return;
  int ai = 0;
  for (int i = 1; i < NCVT; i++) if (gid >= a.off[i]) ai = i;
  int i = gid - a.off[ai];
  float v = 0.f;
  if (i < a.nreal[ai])
    v = f ? ((const float*)a.s[ai])[i] : bf2f(((const u16*)a.s[ai])[i]);
  dst[gid] = v;
}

// ---------------------------------------------------------------- prep: f32 -> packed f16 weights
__global__ void k_prep(const float* __restrict__ WHH1, const float* __restrict__ WHH2,
                       const float* __restrict__ AW,   const float* __restrict__ ALW,
                       u16* __restrict__ WHH1h, u16* __restrict__ WHH2h,
                       u16* __restrict__ AWh,   u16* __restrict__ ALWh){
  int gid = blockIdx.x*256 + threadIdx.x;
  if (gid < 49152){
    WHH1h[gid] = f2h(WHH1[gid]);
    WHH2h[gid] = f2h(WHH2[gid]);
    AWh[gid]   = f2h(AW[gid]);
  }
  if (gid < 16384) ALWh[gid] = f2h(ALW[gid]);
}

// ---------------------------------------------------------------- K1: hop aggregation (f16 dot2)
template<int ROWS>
__device__ __forceinline__ void agg_stage_h(const u16* __restrict__ tmph,
    const u16* __restrict__ Wh, const float* __restrict__ bg,
    u16* __restrict__ outh, int c)
{
  float bias = bg[c];
  float acc[ROWS];
  #pragma unroll
  for (int r = 0; r < ROWS; r++) acc[r] = bias;
  const uint4* wp = (const uint4*)(Wh + c*128);   // 16 x (8 f16)
  #pragma unroll 4
  for (int i = 0; i < 16; i++){
    uint4 wv = wp[i];
    #pragma unroll
    for (int r = 0; r < ROWS; r++){
      uint4 hv = *(const uint4*)(tmph + r*128 + i*8);   // broadcast read
      acc[r] = dot2f(wv.x, hv.x, acc[r]);
      acc[r] = dot2f(wv.y, hv.y, acc[r]);
      acc[r] = dot2f(wv.z, hv.z, acc[r]);
      acc[r] = dot2f(wv.w, hv.w, acc[r]);
    }
  }
  #pragma unroll
  for (int r = 0; r < ROWS; r++)
    outh[r*128 + c] = f2h(fast_tanh(acc[r]));
}

__launch_bounds__(256, 4)
__global__ void k_agg(const int* __restrict__ question,
                      const int* __restrict__ q_neighbors,
                      const int* __restrict__ s_neighbors,
                      const float* __restrict__ EQ,
                      const float* __restrict__ EC,
                      const u16* __restrict__ AWh,
                      const float* __restrict__ AB,
                      const u16* __restrict__ ALWh,
                      const float* __restrict__ ALB,
                      const void* __restrict__ maskp,
                      const int* __restrict__ flags,
                      float* __restrict__ EQREC)
{
  __shared__ __align__(16) u16 e0h[2][128];
  __shared__ __align__(16) u16 e1h[2][512];
  __shared__ __align__(16) u16 e2h[2][2048];
  __shared__ __align__(16) u16 tmph[2][2048];
  __shared__ int nn1[2][4]; __shared__ int nn2[2][16]; __shared__ int nn3[2][64];
  const int tid  = threadIdx.x;
  const int c    = tid & 127;
  const int half = tid >> 7;
  const int bs   = blockIdx.x*2 + half;
  const int n0   = question[bs];
  u16* tp = tmph[half];

  if (c < 4) nn1[half][c] = q_neighbors[n0*4 + c];
  __syncthreads();
  if (c < 16) nn2[half][c] = s_neighbors[nn1[half][c>>2]*4 + (c&3)];
  __syncthreads();
  if (c < 64) nn3[half][c] = q_neighbors[nn2[half][c>>2]*4 + (c&3)];
  e0h[half][c] = f2h(EQ[n0*128 + c]);
  #pragma unroll
  for (int r = 0; r < 4; r++)  e1h[half][r*128 + c] = f2h(EC[nn1[half][r]*128 + c]);
  #pragma unroll 4
  for (int r = 0; r < 16; r++) e2h[half][r*128 + c] = f2h(EQ[nn2[half][r]*128 + c]);
  __syncthreads();

  auto fill_e0 = [&](){
    float v = 0.25f*(h2f(e1h[half][c]) + h2f(e1h[half][128+c])
                   + h2f(e1h[half][256+c]) + h2f(e1h[half][384+c]))
            + h2f(e0h[half][c]);
    tp[c] = f2h(v);
  };
  auto fill_e1 = [&](){
    #pragma unroll
    for (int r = 0; r < 4; r++){
      float v = 0.25f*(h2f(e2h[half][(4*r)*128+c])   + h2f(e2h[half][(4*r+1)*128+c])
                     + h2f(e2h[half][(4*r+2)*128+c]) + h2f(e2h[half][(4*r+3)*128+c]))
              + h2f(e1h[half][r*128 + c]);
      tp[r*128 + c] = f2h(v);
    }
  };

  // i=0: j=0,1,2
  fill_e0(); __syncthreads();
  agg_stage_h<1>(tp, AWh, AB, e0h[half], c); __syncthreads();
  fill_e1(); __syncthreads();
  agg_stage_h<4>(tp, AWh + 16384, AB + 128, e1h[half], c); __syncthreads();
  #pragma unroll 2
  for (int r = 0; r < 16; r++){
    float m = 0.25f*( EC[nn3[half][4*r]*128+c]   + EC[nn3[half][4*r+1]*128+c]
                    + EC[nn3[half][4*r+2]*128+c] + EC[nn3[half][4*r+3]*128+c] );
    tp[r*128 + c] = f2h(m + h2f(e2h[half][r*128 + c]));
  }
  __syncthreads();
  agg_stage_h<16>(tp, AWh + 32768, AB + 256, e2h[half], c); __syncthreads();
  // i=1: j=0,1
  fill_e0(); __syncthreads();
  agg_stage_h<1>(tp, AWh, AB, e0h[half], c); __syncthreads();
  fill_e1(); __syncthreads();
  agg_stage_h<4>(tp, AWh + 16384, AB + 128, e1h[half], c); __syncthreads();
  // i=2: j=0
  fill_e0(); __syncthreads();
  agg_stage_h<1>(tp, AWh, AB, e0h[half], c); __syncthreads();
  // agg = tanh(e0 @ ALW.T + ALB)
  agg_stage_h<1>(e0h[half], ALWh, ALB, tp, c); __syncthreads();
  const int msk = readBool(maskp, bs, flags[1]);
  EQREC[bs*128 + c] = msk ? h2f(tp[c]) : EQ[n0*128 + c];
}

// ---------------------------------------------------------------- K2: gi1 precompute (K=256)
__launch_bounds__(384, 1)
__global__ void k_gi1(const float* __restrict__ EQREC,
                      const int* __restrict__ response,
                      const float* __restrict__ ECOR,
                      const float* __restrict__ WIH1,
                      const float* __restrict__ BIH1,
                      float* __restrict__ GI1)
{
  const int t  = blockIdx.x;
  const int bg = blockIdx.y;
  const int tid = threadIdx.x;
  __shared__ __align__(16) float X[8][256];
  for (int o = tid; o < 2048; o += 384){
    int bb = o >> 8, k = o & 255;
    int b = bg*8 + bb;
    X[bb][k] = (k < 128) ? EQREC[(b*S_ + t)*128 + k]
                         : ECOR[response[b*S_ + t]*128 + (k - 128)];
  }
  __syncthreads();
  float bias = BIH1[tid];
  float acc[8];
  #pragma unroll
  for (int i = 0; i < 8; i++) acc[i] = bias;
  const float4* wp = (const float4*)(WIH1 + tid*256);
  #pragma unroll 2
  for (int i8 = 0; i8 < 64; i8 += 2){
    float4 v0 = wp[i8], v1 = wp[i8+1];
    float wv[8] = {v0.x,v0.y,v0.z,v0.w,v1.x,v1.y,v1.z,v1.w};
    int k0 = i8*4;
    #pragma unroll
    for (int bb = 0; bb < 8; bb++){
      #pragma unroll
      for (int kq = 0; kq < 8; kq++)
        acc[bb] = fmaf(X[bb][k0 + kq], wv[kq], acc[bb]);
    }
  }
  #pragma unroll
  for (int bb = 0; bb < 8; bb++)
    GI1[(t*32 + bg*8 + bb)*384 + tid] = acc[bb];
}

// ---------------------------------------------------------------- K2b: gi2 precompute (K=128)
__launch_bounds__(384, 1)
__global__ void k_gi2(const float* __restrict__ H1ALL,
                      const float* __restrict__ WIH2,
                      const float* __restrict__ BIH2,
                      float* __restrict__ GI2)
{
  const int t  = blockIdx.x;
  const int bg = blockIdx.y;
  const int tid = threadIdx.x;
  __shared__ __align__(16) float X[8][128];
  for (int o = tid; o < 1024; o += 384){
    int bb = o >> 7, k = o & 127;
    int b = bg*8 + bb;
    X[bb][k] = H1ALL[(t*32 + b)*128 + k];
  }
  __syncthreads();
  float bias = BIH2[tid];
  float acc[8];
  #pragma unroll
  for (int i = 0; i < 8; i++) acc[i] = bias;
  const float4* wp = (const float4*)(WIH2 + tid*128);
  #pragma unroll 2
  for (int i8 = 0; i8 < 32; i8 += 2){
    float4 v0 = wp[i8], v1 = wp[i8+1];
    float wv[8] = {v0.x,v0.y,v0.z,v0.w,v1.x,v1.y,v1.z,v1.w};
    int k0 = i8*4;
    #pragma unroll
    for (int bb = 0; bb < 8; bb++){
      #pragma unroll
      for (int kq = 0; kq < 8; kq++)
        acc[bb] = fmaf(X[bb][k0 + kq], wv[kq], acc[bb]);
    }
  }
  #pragma unroll
  for (int bb = 0; bb < 8; bb++)
    GI2[(t*32 + bg*8 + bb)*384 + tid] = acc[bb];
}

// ---------------------------------------------------------------- K3: scores + top-10
__global__ void k_topk(const int* __restrict__ question,
                       const float* __restrict__ EQ,
                       int* __restrict__ IDX)
{
  const int blk = blockIdx.x;
  const int t = blk >> 5, b = blk & 31;
  const int tid = threadIdx.x;               // 64
  __shared__ __align__(16) float qn[128];
  const int qid = question[b*S_ + t + 1];
  for (int o = tid; o < 128; o += 64) qn[o] = EQ[qid*128 + o];
  __syncthreads();
  float val[4]; int sv[4];
  #pragma unroll
  for (int i = 0; i < 4; i++){
    int s = tid + 64*i;
    sv[i] = s;
    float v = -3.0e38f;
    if (s < S_) v = (s < t) ? dot128f(EQ + question[b*S_ + s]*128, qn) : NEGV;
    val[i] = v;
  }
  for (int r = 0; r < 10; r++){
    float bv = -3.0e38f; int bi = 0x3fffffff;
    #pragma unroll
    for (int i = 0; i < 4; i++){
      if (val[i] > bv || (val[i] == bv && sv[i] < bi)){ bv = val[i]; bi = sv[i]; }
    }
    for (int off = 32; off; off >>= 1){
      float ov = __shfl_down(bv, off);
      int   oi = __shfl_down(bi, off);
      if (ov > bv || (ov == bv && oi < bi)){ bv = ov; bi = oi; }
    }
    int win = __shfl(bi, 0);
    if (tid == 0) IDX[blk*10 + r] = win;
    #pragma unroll
    for (int i = 0; i < 4; i++) if (sv[i] == win) val[i] = -3.0e38f;
  }
}

// ---------------------------------------------------------------- K4a: h1 chain (f16 dot2)
__launch_bounds__(384, 1)
__global__ void k_chain1(const float* __restrict__ GI1,
                         const u16* __restrict__ WHH1h,
                         const float* __restrict__ BHH1,
                         const float* __restrict__ H1I,
                         float* __restrict__ H1ALL)
{
  const int b = blockIdx.x;
  const int tid = threadIdx.x;
  __shared__ __align__(16) float h[128];
  __shared__ __align__(16) u16 hh[128];
  __shared__ float gh[384];
  if (tid < 128){ float v = H1I[b*128 + tid]; h[tid] = v; hh[tid] = f2h(v); }
  const float bias = BHH1[tid];
  u32 W[64];
  {
    const uint4* wp = (const uint4*)(WHH1h + tid*128);
    #pragma unroll
    for (int i = 0; i < 16; i++){
      uint4 v = wp[i];
      W[4*i] = v.x; W[4*i+1] = v.y; W[4*i+2] = v.z; W[4*i+3] = v.w;
    }
  }
  float irN = 0.f, izN = 0.f, innN = 0.f;
  if (tid < 128){
    const float* gp = GI1 + b*384;
    irN = gp[tid]; izN = gp[128+tid]; innN = gp[256+tid];
  }
  __syncthreads();
  for (int t = 0; t < T_; t++){
    const float ir = irN, iz = izN, inn = innN;
    if (t + 1 < T_ && tid < 128){
      const float* gp = GI1 + ((t+1)*32 + b)*384;
      irN = gp[tid]; izN = gp[128+tid]; innN = gp[256+tid];
    }
    float a = bias, ab = 0.f;
    #pragma unroll
    for (int i = 0; i < 16; i++){
      uint4 hv = *(const uint4*)(hh + i*8);
      a  = dot2f(W[4*i],   hv.x, a);
      ab = dot2f(W[4*i+1], hv.y, ab);
      a  = dot2f(W[4*i+2], hv.z, a);
      ab = dot2f(W[4*i+3], hv.w, ab);
    }
    gh[tid] = a + ab;
    __syncthreads();
    if (tid < 128){
      float r = fast_sigmoid(ir + gh[tid]);
      float z = fast_sigmoid(iz + gh[128+tid]);
      float n = fast_tanh(inn + r*gh[256+tid]);
      float hn = (1.f - z)*n + z*h[tid];
      h[tid] = hn;
      hh[tid] = f2h(hn);
      H1ALL[(t*32 + b)*128 + tid] = hn;
    }
    __syncthreads();
  }
}

// ---------------------------------------------------------------- K4b: h2/g2 chain (f16 dot2)
__launch_bounds__(384, 1)
__global__ void k_chain2(const float* __restrict__ GI2,
                         const u16* __restrict__ WHH2h,
                         const float* __restrict__ BHH2,
                         const float* __restrict__ H2I,
                         float* __restrict__ G2)
{
  const int b = blockIdx.x;
  const int tid = threadIdx.x;
  __shared__ __align__(16) float h[128];
  __shared__ __align__(16) u16 hh[128];
  __shared__ float gh[384];
  if (tid < 128){ float v = H2I[b*128 + tid]; h[tid] = v; hh[tid] = f2h(v); }
  const float bias = BHH2[tid];
  u32 W[64];
  {
    const uint4* wp = (const uint4*)(WHH2h + tid*128);
    #pragma unroll
    for (int i = 0; i < 16; i++){
      uint4 v = wp[i];
      W[4*i] = v.x; W[4*i+1] = v.y; W[4*i+2] = v.z; W[4*i+3] = v.w;
    }
  }
  float irN = 0.f, izN = 0.f, innN = 0.f;
  if (tid < 128){
    const float* gp = GI2 + b*384;
    irN = gp[tid]; izN = gp[128+tid]; innN = gp[256+tid];
  }
  __syncthreads();
  for (int t = 0; t < T_; t++){
    const float ir = irN, iz = izN, inn = innN;
    if (t + 1 < T_ && tid < 128){
      const float* gp = GI2 + ((t+1)*32 + b)*384;
      irN = gp[tid]; izN = gp[128+tid]; innN = gp[256+tid];
    }
    float a = bias, ab = 0.f;
    #pragma unroll
    for (int i = 0; i < 16; i++){
      uint4 hv = *(const uint4*)(hh + i*8);
      a  = dot2f(W[4*i],   hv.x, a);
      ab = dot2f(W[4*i+1], hv.y, ab);
      a  = dot2f(W[4*i+2], hv.z, a);
      ab = dot2f(W[4*i+3], hv.w, ab);
    }
    gh[tid] = a + ab;
    __syncthreads();
    if (tid < 128){
      float r2 = fast_sigmoid(ir + gh[tid]);
      float z2 = fast_sigmoid(iz + gh[128+tid]);
      float n2 = fast_tanh(inn + r2*gh[256+tid]);
      float g = (1.f - z2)*n2 + z2*h[tid];
      G2[(t*32 + b)*128 + tid] = g;
      if (t > 0){ h[tid] = g; hh[tid] = f2h(g); }
    }
    __syncthreads();
  }
}

// ---------------------------------------------------------------- K5: Kp·w_k for all G2 rows
// softmax-shift cancellation: Qp·w_q + bias is constant along the softmax
// axis -> QPW is dead. Only Kp·w_k survives. 8 rows/block amortizes the
// QW row read 8x (r9: per-row streaming made k_qkw latency-bound at 284 us).
__launch_bounds__(128, 4)
__global__ void k_kp(const float* __restrict__ G2,
                     const float* __restrict__ QW, const float* __restrict__ QB,
                     const float* __restrict__ MW,
                     float* __restrict__ KPWG)
{
  __shared__ __align__(16) float X[8][128];
  __shared__ float red[8][2];
  const int tid = threadIdx.x;           // c in [0,128)
  const int base = blockIdx.x * 8;       // 796 blocks x 8 rows = 6368
  for (int o = tid; o < 1024; o += 128){
    int r = o >> 7, c = o & 127;
    X[r][c] = G2[(base + r)*128 + c];
  }
  __syncthreads();
  float acc[8];
  float bias = QB[tid];
  #pragma unroll
  for (int r = 0; r < 8; r++) acc[r] = bias;
  const float4* wp = (const float4*)(QW + tid*128);
  #pragma unroll 4
  for (int i4 = 0; i4 < 32; i4++){
    float4 wv = wp[i4];
    int kk = 4*i4;
    #pragma unroll
    for (int r = 0; r < 8; r++){
      float4 t4 = *(const float4*)(&X[r][kk]);
      acc[r] = fmaf(t4.x, wv.x, acc[r]);
      acc[r] = fmaf(t4.y, wv.y, acc[r]);
      acc[r] = fmaf(t4.z, wv.z, acc[r]);
      acc[r] = fmaf(t4.w, wv.w, acc[r]);
    }
  }
  const float wk = MW[128 + tid];
  const int lane = tid & 63, wv_ = tid >> 6;
  #pragma unroll
  for (int r = 0; r < 8; r++){
    float pv = fast_tanh(acc[r]) * wk;
    for (int off = 32; off; off >>= 1) pv += __shfl_down(pv, off);
    if (lane == 0) red[r][wv_] = pv;
  }
  __syncthreads();
  if (tid < 8) KPWG[base + tid] = red[tid][0] + red[tid][1];
}

// ---------------------------------------------------------------- K6: predict + output
// alpha = softmax_s(kpw_s) (Qp-term cancels); p = sum_s alpha_s (qcsum.hist_s)
__global__ void k_pred(const int* __restrict__ question,
                       const int* __restrict__ qci, const void* __restrict__ qcm,
                       const int* __restrict__ flags,
                       const float* __restrict__ EQ, const float* __restrict__ EC,
                       const float* __restrict__ QB, const float* __restrict__ MW,
                       const float* __restrict__ G2,
                       const int* __restrict__ IDX,
                       const float* __restrict__ KPWG,
                       void* __restrict__ outp)
{
  const int blk = blockIdx.x;
  const int t = blk >> 5, b = blk & 31;
  const int tid = threadIdx.x;               // 64
  __shared__ float hist[11][132];
  __shared__ float qcs[128];
  __shared__ float og[11];
  __shared__ float kpw[11];
  __shared__ int   idxs[10];
  __shared__ float kpw0s;
  const int qid = question[b*S_ + t + 1];
  const int bflag = flags[1];
  if (tid < 10) idxs[tid] = IDX[blk*10 + tid];
  __syncthreads();
  for (int o = tid; o < 11*128; o += 64){
    int k = o >> 7, c = o & 127;
    float v;
    if (k == 0) v = G2[blk*128 + c];
    else { int s = idxs[k-1]; v = (s == 0) ? 0.f : G2[(s*32 + b)*128 + c]; }
    hist[k][c] = v;
  }
  #pragma unroll
  for (int o = tid; o < 128; o += 64){
    float v = EQ[qid*128 + o];
    #pragma unroll
    for (int q = 0; q < 4; q++){
      if (readBool(qcm, qid*4 + q, bflag))
        v += EC[qci[qid*4 + q]*128 + o];
    }
    qcs[o] = v;
  }
  {
    float pv = fast_tanh(QB[tid])      * MW[128 + tid]
             + fast_tanh(QB[tid + 64]) * MW[128 + tid + 64];
    for (int off = 32; off; off >>= 1) pv += __shfl_down(pv, off);
    if (tid == 0) kpw0s = pv;
  }
  __syncthreads();
  if (tid < 11){
    float acc = 0.f;
    for (int c = 0; c < 128; c++) acc = fmaf(qcs[c], hist[tid][c], acc);
    og[tid] = acc;
    float v;
    if (tid == 0) v = KPWG[blk];
    else { int s = idxs[tid-1]; v = (s == 0) ? kpw0s : KPWG[s*32 + b]; }
    kpw[tid] = v;
  }
  __syncthreads();
  if (tid == 0){
    float tv[11];
    #pragma unroll
    for (int k = 0; k < 11; k++){
      int valid = (k == 0) || (idxs[k-1] < t);
      tv[k] = valid ? kpw[k] : NEGV;
    }
    float m = tv[0];
    #pragma unroll
    for (int k = 1; k < 11; k++) m = fmaxf(m, tv[k]);
    float den = 0.f, num = 0.f;
    #pragma unroll
    for (int k = 0; k < 11; k++){
      float e = __expf(tv[k] - m);
      den += e;
      num = fmaf(e, og[k], num);
    }
    float p = num / den;
    int col = (t == 0) ? 0 : (t + 1);
    if (flags[0]){
      ((float*)outp)[b*S_ + col] = p;
      if (t == 0) ((float*)outp)[b*S_ + 1] = 0.f;
    } else {
      ((u16*)outp)[b*S_ + col] = f2bf(p);
      if (t == 0) ((u16*)outp)[b*S_ + 1] = (u16)0;
    }
  }
}

// ---------------------------------------------------------------- launcher
extern "C" void kernel_launch(void* const* d_in, const int* in_sizes, int n_in,
                              void* d_out, int out_size, void* d_ws, size_t ws_size,
                              hipStream_t stream)
{
  (void)in_sizes; (void)n_in; (void)out_size; (void)ws_size;
  const int* question      = (const int*)d_in[0];
  const int* response      = (const int*)d_in[1];
  const void* maskp        = d_in[2];
  const int* q_neighbors   = (const int*)d_in[3];
  const int* s_neighbors   = (const int*)d_in[4];
  const int* q_concept_idx = (const int*)d_in[5];
  const void* q_concept_mask = d_in[6];

  static const int CN[NCVT] = {2560000,256000,256,98304,49152,384,384,49152,49152,
                               384,384,49152,384,16384,128,16384,128,16384,128,
                               256,1,4096,4096};
  CvtArgs ca;
  int off = 0;
  for (int i = 0; i < NCVT; i++){
    ca.s[i] = d_in[7 + i];
    ca.nreal[i] = CN[i];
    ca.off[i] = off;
    off += (CN[i] + 3) & ~3;
  }
  ca.off[NCVT] = off;
  const int total = off;

  char* ws = (char*)d_ws;
  size_t wo = 0;
  auto alloc = [&](size_t bytes) -> void* {
    void* p = ws + wo;
    wo = (wo + bytes + 255) & ~(size_t)255;
    return p;
  };
  int*   flags = (int*)  alloc(16);
  float* CVT   = (float*)alloc((size_t)total * 4);
  float* EQREC = (float*)alloc((size_t)B_*S_*D_*4);
  float* GI1   = (float*)alloc((size_t)T_*B_*384*4);
  float* GI2A  = (float*)alloc((size_t)T_*B_*384*4);
  float* H1ALL = (float*)alloc((size_t)T_*B_*D_*4);
  float* G2    = (float*)alloc((size_t)T_*B_*D_*4);
  int*   IDX   = (int*)  alloc((size_t)T_*B_*10*4);
  float* KPWG  = (float*)alloc((size_t)T_*B_*4);
  u16*   WHH1h = (u16*)  alloc(49152*2);
  u16*   WHH2h = (u16*)  alloc(49152*2);
  u16*   AWh   = (u16*)  alloc(49152*2);
  u16*   ALWh  = (u16*)  alloc(16384*2);

  const float* EQ   = CVT + ca.off[0];
  const float* EC   = CVT + ca.off[1];
  const float* ECOR = CVT + ca.off[2];
  const float* WIH1 = CVT + ca.off[3];
  const float* WHH1 = CVT + ca.off[4];
  const float* BIH1 = CVT + ca.off[5];
  const float* BHH1 = CVT + ca.off[6];
  const float* WIH2 = CVT + ca.off[7];
  const float* WHH2 = CVT + ca.off[8];
  const float* BIH2 = CVT + ca.off[9];
  const float* BHH2 = CVT + ca.off[10];
  const float* AW   = CVT + ca.off[11];
  const float* AB   = CVT + ca.off[12];
  const float* ALW  = CVT + ca.off[13];
  const float* ALB  = CVT + ca.off[14];
  const float* QW   = CVT + ca.off[15];
  const float* QB   = CVT + ca.off[16];
  const float* MW   = CVT + ca.off[19];
  const float* H1I  = CVT + ca.off[21];
  const float* H2I  = CVT + ca.off[22];

  k_sniff2<<<1, 256, 0, stream>>>((const u16*)d_in[7], (const unsigned char*)maskp, flags);
  k_cvt<<<(total + 255)/256, 256, 0, stream>>>(ca, flags, CVT);
  k_prep<<<192, 256, 0, stream>>>(WHH1, WHH2, AW, ALW, WHH1h, WHH2h, AWh, ALWh);
  k_agg<<<B_*S_/2, 256, 0, stream>>>(question, q_neighbors, s_neighbors, EQ, EC,
                                     AWh, AB, ALWh, ALB, maskp, flags, EQREC);
  k_gi1<<<dim3(T_, 4), 384, 0, stream>>>(EQREC, response, ECOR, WIH1, BIH1, GI1);
  k_topk<<<T_*B_, 64, 0, stream>>>(question, EQ, IDX);
  k_chain1<<<B_, 384, 0, stream>>>(GI1, WHH1h, BHH1, H1I, H1ALL);
  k_gi2<<<dim3(T_, 4), 384, 0, stream>>>(H1ALL, WIH2, BIH2, GI2A);
  k_chain2<<<B_, 384, 0, stream>>>(GI2A, WHH2h, BHH2, H2I, G2);
  k_kp<<<T_*B_/8, 128, 0, stream>>>(G2, QW, QB, MW, KPWG);
  k_pred<<<T_*B_, 64, 0, stream>>>(question, q_concept_idx, q_concept_mask, flags,
                                   EQ, EC, QB, MW, G2, IDX, KPWG, d_out);
}

// Round 11
// 717.536 us; speedup vs baseline: 2.1573x; 1.0810x over previous
//
#include <hip/hip_runtime.h>
#include <math.h>

typedef unsigned short u16;
typedef unsigned int   u32;
typedef __attribute__((ext_vector_type(2))) _Float16 half2_t;

#define B_   32
#define S_   200
#define D_   128
#define T_   199
#define NEGV (-1e30f)

__device__ __forceinline__ float bf2f(u16 u){
  union { u32 i; float f; } v; v.i = ((u32)u) << 16; return v.f;
}
__device__ __forceinline__ u16 f2bf(float f){
  union { float f; u32 i; } v; v.f = f;
  u32 x = v.i;
  return (u16)((x + 0x7fffu + ((x >> 16) & 1u)) >> 16);   // RNE
}
__device__ __forceinline__ u16 f2h(float x){
  union { _Float16 h; u16 u; } v; v.h = (_Float16)x; return v.u;
}
__device__ __forceinline__ float h2f(u16 u){
  union { u16 u; _Float16 h; } v; v.u = u; return (float)v.h;
}
// 2 MACs/instr: f32 += f16x2 . f16x2  (v_dot2_f32_f16)
__device__ __forceinline__ float dot2f(u32 w, u32 h, float acc){
#if __has_builtin(__builtin_amdgcn_fdot2)
  union { u32 u; half2_t h2; } a, b;
  a.u = w; b.u = h;
  return __builtin_amdgcn_fdot2(a.h2, b.h2, acc, false);
#else
  union { u32 u; _Float16 f[2]; } a, b;
  a.u = w; b.u = h;
  acc = fmaf((float)a.f[0], (float)b.f[0], acc);
  return fmaf((float)a.f[1], (float)b.f[1], acc);
#endif
}
__device__ __forceinline__ float fast_sigmoid(float x){ return 1.f/(1.f+__expf(-x)); }
__device__ __forceinline__ float fast_tanh(float x){
  float e = __expf(2.f*x);
  return 1.f - 2.f/(e + 1.f);
}

// bool storage modes: 0=int32, 1=u8, 2=bf16, 3=f32
__device__ __forceinline__ int readBool(const void* p, int i, int m){
  if (m == 0) return ((const int*)p)[i] != 0;
  if (m == 1) return ((const unsigned char*)p)[i] != 0;
  if (m == 2) return ((const u16*)p)[i] != 0;
  return ((const u32*)p)[i] != 0;
}

__device__ __forceinline__ float dot128f(const float* __restrict__ w,
                                         const float* __restrict__ x){
  float acc = 0.f;
  const float4* wp = (const float4*)w;
  #pragma unroll 8
  for (int i = 0; i < 32; i++){
    float4 v = wp[i]; int k = 4*i;
    acc = fmaf(v.x, x[k],   acc);
    acc = fmaf(v.y, x[k+1], acc);
    acc = fmaf(v.z, x[k+2], acc);
    acc = fmaf(v.w, x[k+3], acc);
  }
  return acc;
}

// ---------------------------------------------------------------- sniffer
__global__ void k_sniff2(const u16* __restrict__ embq_raw,
                         const unsigned char* __restrict__ mask_raw,
                         int* __restrict__ flags){
  __shared__ int bad, gt1, m4, b0;
  const int tid = threadIdx.x;
  if (tid == 0){ bad = 0; gt1 = 0; m4 = 0; b0 = 0; }
  __syncthreads();
  for (int i = tid; i < 512; i += 256){
    u16 u = embq_raw[i];
    if (u){ int e = (u >> 7) & 0xFF; if (e < 0x58 || e > 0x7F) atomicAdd(&bad, 1); }
  }
  for (int i = tid; i < 1024; i += 256){
    unsigned char c = mask_raw[i];
    if (c > 1) atomicAdd(&gt1, 1);
    if (c && (i & 3)) atomicAdd(&m4, 1);
    if (c && !(i & 3)) atomicAdd(&b0, 1);
  }
  __syncthreads();
  if (tid == 0){
    flags[0] = (bad >= 16) ? 1 : 0;
    flags[1] = gt1 ? (b0 ? 2 : 3) : (m4 ? 1 : 0);
  }
}

// ---------------------------------------------------------------- convert floats -> f32
#define NCVT 23
struct CvtArgs { const void* s[NCVT]; int off[NCVT+1]; int nreal[NCVT]; };

__global__ void k_cvt(CvtArgs a, const int* __restrict__ flags, float* __restrict__ dst){
  __shared__ int f;
  if (threadIdx.x == 0) f = flags[0];
  __syncthreads();
  int gid = blockIdx.x * 256 + threadIdx.x;
  if (gid >= a.off[NCVT]) return;
  int ai = 0;
  for (int i = 1; i < NCVT; i++) if (gid >= a.off[i]) ai = i;
  int i = gid - a.off[ai];
  float v = 0.f;
  if (i < a.nreal[ai])
    v = f ? ((const float*)a.s[ai])[i] : bf2f(((const u16*)a.s[ai])[i]);
  dst[gid] = v;
}

// ---------------------------------------------------------------- prep: f32 -> packed f16 weights
__global__ void k_prep(const float* __restrict__ WHH1, const float* __restrict__ WHH2,
                       const float* __restrict__ AW,   const float* __restrict__ ALW,
                       const float* __restrict__ WIH1, const float* __restrict__ WIH2,
                       u16* __restrict__ WHH1h, u16* __restrict__ WHH2h,
                       u16* __restrict__ AWh,   u16* __restrict__ ALWh,
                       u16* __restrict__ WIH1h, u16* __restrict__ WIH2h){
  int gid = blockIdx.x*256 + threadIdx.x;
  if (gid < 49152){
    WHH1h[gid] = f2h(WHH1[gid]);
    WHH2h[gid] = f2h(WHH2[gid]);
    AWh[gid]   = f2h(AW[gid]);
    WIH2h[gid] = f2h(WIH2[gid]);
  }
  if (gid < 16384) ALWh[gid] = f2h(ALW[gid]);
  if (gid < 98304) WIH1h[gid] = f2h(WIH1[gid]);
}

// ---------------------------------------------------------------- K1: hop aggregation (f16 dot2)
// ROWS<=4 stages: serial dot2 chain was the stall (1 acc x 64 dot2 x ~4cyc
// latency) -> split into 2 partial accumulators. ROWS=16 already has 16-way
// ILP; single acc protects VGPRs. SPILL RULES: weight loop keeps unroll 4.
template<int ROWS>
__device__ __forceinline__ void agg_stage_h(const u16* __restrict__ tmph,
    const u16* __restrict__ Wh, const float* __restrict__ bg,
    u16* __restrict__ outh, int c)
{
  float bias = bg[c];
  float acc[ROWS];
  #pragma unroll
  for (int r = 0; r < ROWS; r++) acc[r] = bias;
  const uint4* wp = (const uint4*)(Wh + c*128);   // 16 x (8 f16)
  if constexpr (ROWS <= 4){
    float acc2[ROWS];
    #pragma unroll
    for (int r = 0; r < ROWS; r++) acc2[r] = 0.f;
    #pragma unroll 4
    for (int i = 0; i < 16; i++){
      uint4 wv = wp[i];
      #pragma unroll
      for (int r = 0; r < ROWS; r++){
        uint4 hv = *(const uint4*)(tmph + r*128 + i*8);
        acc[r]  = dot2f(wv.x, hv.x, acc[r]);
        acc2[r] = dot2f(wv.y, hv.y, acc2[r]);
        acc[r]  = dot2f(wv.z, hv.z, acc[r]);
        acc2[r] = dot2f(wv.w, hv.w, acc2[r]);
      }
    }
    #pragma unroll
    for (int r = 0; r < ROWS; r++)
      outh[r*128 + c] = f2h(fast_tanh(acc[r] + acc2[r]));
  } else {
    #pragma unroll 4
    for (int i = 0; i < 16; i++){
      uint4 wv = wp[i];
      #pragma unroll
      for (int r = 0; r < ROWS; r++){
        uint4 hv = *(const uint4*)(tmph + r*128 + i*8);   // broadcast read
        acc[r] = dot2f(wv.x, hv.x, acc[r]);
        acc[r] = dot2f(wv.y, hv.y, acc[r]);
        acc[r] = dot2f(wv.z, hv.z, acc[r]);
        acc[r] = dot2f(wv.w, hv.w, acc[r]);
      }
    }
    #pragma unroll
    for (int r = 0; r < ROWS; r++)
      outh[r*128 + c] = f2h(fast_tanh(acc[r]));
  }
}

__launch_bounds__(256, 4)
__global__ void k_agg(const int* __restrict__ question,
                      const int* __restrict__ q_neighbors,
                      const int* __restrict__ s_neighbors,
                      const float* __restrict__ EQ,
                      const float* __restrict__ EC,
                      const u16* __restrict__ AWh,
                      const float* __restrict__ AB,
                      const u16* __restrict__ ALWh,
                      const float* __restrict__ ALB,
                      const void* __restrict__ maskp,
                      const int* __restrict__ flags,
                      float* __restrict__ EQREC)
{
  __shared__ __align__(16) u16 e0h[2][128];
  __shared__ __align__(16) u16 e1h[2][512];
  __shared__ __align__(16) u16 e2h[2][2048];
  __shared__ __align__(16) u16 tmph[2][2048];
  __shared__ int nn1[2][4]; __shared__ int nn2[2][16]; __shared__ int nn3[2][64];
  const int tid  = threadIdx.x;
  const int c    = tid & 127;
  const int half = tid >> 7;
  const int bs   = blockIdx.x*2 + half;
  const int n0   = question[bs];
  u16* tp = tmph[half];

  if (c < 4) nn1[half][c] = q_neighbors[n0*4 + c];
  __syncthreads();
  if (c < 16) nn2[half][c] = s_neighbors[nn1[half][c>>2]*4 + (c&3)];
  __syncthreads();
  if (c < 64) nn3[half][c] = q_neighbors[nn2[half][c>>2]*4 + (c&3)];
  e0h[half][c] = f2h(EQ[n0*128 + c]);
  #pragma unroll
  for (int r = 0; r < 4; r++)  e1h[half][r*128 + c] = f2h(EC[nn1[half][r]*128 + c]);
  #pragma unroll 4
  for (int r = 0; r < 16; r++) e2h[half][r*128 + c] = f2h(EQ[nn2[half][r]*128 + c]);
  __syncthreads();

  auto fill_e0 = [&](){
    float v = 0.25f*(h2f(e1h[half][c]) + h2f(e1h[half][128+c])
                   + h2f(e1h[half][256+c]) + h2f(e1h[half][384+c]))
            + h2f(e0h[half][c]);
    tp[c] = f2h(v);
  };
  auto fill_e1 = [&](){
    #pragma unroll
    for (int r = 0; r < 4; r++){
      float v = 0.25f*(h2f(e2h[half][(4*r)*128+c])   + h2f(e2h[half][(4*r+1)*128+c])
                     + h2f(e2h[half][(4*r+2)*128+c]) + h2f(e2h[half][(4*r+3)*128+c]))
              + h2f(e1h[half][r*128 + c]);
      tp[r*128 + c] = f2h(v);
    }
  };

  // i=0: j=0,1,2
  fill_e0(); __syncthreads();
  agg_stage_h<1>(tp, AWh, AB, e0h[half], c); __syncthreads();
  fill_e1(); __syncthreads();
  agg_stage_h<4>(tp, AWh + 16384, AB + 128, e1h[half], c); __syncthreads();
  #pragma unroll 2
  for (int r = 0; r < 16; r++){
    float m = 0.25f*( EC[nn3[half][4*r]*128+c]   + EC[nn3[half][4*r+1]*128+c]
                    + EC[nn3[half][4*r+2]*128+c] + EC[nn3[half][4*r+3]*128+c] );
    tp[r*128 + c] = f2h(m + h2f(e2h[half][r*128 + c]));
  }
  __syncthreads();
  agg_stage_h<16>(tp, AWh + 32768, AB + 256, e2h[half], c); __syncthreads();
  // i=1: j=0,1
  fill_e0(); __syncthreads();
  agg_stage_h<1>(tp, AWh, AB, e0h[half], c); __syncthreads();
  fill_e1(); __syncthreads();
  agg_stage_h<4>(tp, AWh + 16384, AB + 128, e1h[half], c); __syncthreads();
  // i=2: j=0
  fill_e0(); __syncthreads();
  agg_stage_h<1>(tp, AWh, AB, e0h[half], c); __syncthreads();
  // agg = tanh(e0 @ ALW.T + ALB)
  agg_stage_h<1>(e0h[half], ALWh, ALB, tp, c); __syncthreads();
  const int msk = readBool(maskp, bs, flags[1]);
  EQREC[bs*128 + c] = msk ? h2f(tp[c]) : EQ[n0*128 + c];
}

// ---------------------------------------------------------------- K2: gi1 precompute (K=256, f16 dot2)
__launch_bounds__(384, 1)
__global__ void k_gi1(const float* __restrict__ EQREC,
                      const int* __restrict__ response,
                      const float* __restrict__ ECOR,
                      const u16* __restrict__ WIH1h,
                      const float* __restrict__ BIH1,
                      float* __restrict__ GI1)
{
  const int t  = blockIdx.x;
  const int bg = blockIdx.y;
  const int tid = threadIdx.x;
  __shared__ __align__(16) u16 X[8][256];
  for (int o = tid; o < 2048; o += 384){
    int bb = o >> 8, k = o & 255;
    int b = bg*8 + bb;
    float v = (k < 128) ? EQREC[(b*S_ + t)*128 + k]
                        : ECOR[response[b*S_ + t]*128 + (k - 128)];
    X[bb][k] = f2h(v);
  }
  __syncthreads();
  float bias = BIH1[tid];
  float acc[8];
  #pragma unroll
  for (int i = 0; i < 8; i++) acc[i] = bias;
  const uint4* wp = (const uint4*)(WIH1h + tid*256);   // 32 x (8 f16)
  #pragma unroll 4
  for (int i = 0; i < 32; i++){
    uint4 wv = wp[i];
    #pragma unroll
    for (int bb = 0; bb < 8; bb++){
      uint4 hv = *(const uint4*)(&X[bb][i*8]);   // broadcast
      acc[bb] = dot2f(wv.x, hv.x, acc[bb]);
      acc[bb] = dot2f(wv.y, hv.y, acc[bb]);
      acc[bb] = dot2f(wv.z, hv.z, acc[bb]);
      acc[bb] = dot2f(wv.w, hv.w, acc[bb]);
    }
  }
  #pragma unroll
  for (int bb = 0; bb < 8; bb++)
    GI1[(t*32 + bg*8 + bb)*384 + tid] = acc[bb];
}

// ---------------------------------------------------------------- K2b: gi2 precompute (K=128, f16 dot2)
__launch_bounds__(384, 1)
__global__ void k_gi2(const float* __restrict__ H1ALL,
                      const u16* __restrict__ WIH2h,
                      const float* __restrict__ BIH2,
                      float* __restrict__ GI2)
{
  const int t  = blockIdx.x;
  const int bg = blockIdx.y;
  const int tid = threadIdx.x;
  __shared__ __align__(16) u16 X[8][128];
  for (int o = tid; o < 1024; o += 384){
    int bb = o >> 7, k = o & 127;
    int b = bg*8 + bb;
    X[bb][k] = f2h(H1ALL[(t*32 + b)*128 + k]);
  }
  __syncthreads();
  float bias = BIH2[tid];
  float acc[8];
  #pragma unroll
  for (int i = 0; i < 8; i++) acc[i] = bias;
  const uint4* wp = (const uint4*)(WIH2h + tid*128);   // 16 x (8 f16)
  #pragma unroll 4
  for (int i = 0; i < 16; i++){
    uint4 wv = wp[i];
    #pragma unroll
    for (int bb = 0; bb < 8; bb++){
      uint4 hv = *(const uint4*)(&X[bb][i*8]);
      acc[bb] = dot2f(wv.x, hv.x, acc[bb]);
      acc[bb] = dot2f(wv.y, hv.y, acc[bb]);
      acc[bb] = dot2f(wv.z, hv.z, acc[bb]);
      acc[bb] = dot2f(wv.w, hv.w, acc[bb]);
    }
  }
  #pragma unroll
  for (int bb = 0; bb < 8; bb++)
    GI2[(t*32 + bg*8 + bb)*384 + tid] = acc[bb];
}

// ---------------------------------------------------------------- K3: scores + top-10
__global__ void k_topk(const int* __restrict__ question,
                       const float* __restrict__ EQ,
                       int* __restrict__ IDX)
{
  const int blk = blockIdx.x;
  const int t = blk >> 5, b = blk & 31;
  const int tid = threadIdx.x;               // 64
  __shared__ __align__(16) float qn[128];
  const int qid = question[b*S_ + t + 1];
  for (int o = tid; o < 128; o += 64) qn[o] = EQ[qid*128 + o];
  __syncthreads();
  float val[4]; int sv[4];
  #pragma unroll
  for (int i = 0; i < 4; i++){
    int s = tid + 64*i;
    sv[i] = s;
    float v = -3.0e38f;
    if (s < S_) v = (s < t) ? dot128f(EQ + question[b*S_ + s]*128, qn) : NEGV;
    val[i] = v;
  }
  for (int r = 0; r < 10; r++){
    float bv = -3.0e38f; int bi = 0x3fffffff;
    #pragma unroll
    for (int i = 0; i < 4; i++){
      if (val[i] > bv || (val[i] == bv && sv[i] < bi)){ bv = val[i]; bi = sv[i]; }
    }
    for (int off = 32; off; off >>= 1){
      float ov = __shfl_down(bv, off);
      int   oi = __shfl_down(bi, off);
      if (ov > bv || (ov == bv && oi < bi)){ bv = ov; bi = oi; }
    }
    int win = __shfl(bi, 0);
    if (tid == 0) IDX[blk*10 + r] = win;
    #pragma unroll
    for (int i = 0; i < 4; i++) if (sv[i] == win) val[i] = -3.0e38f;
  }
}

// ---------------------------------------------------------------- K4a: h1 chain (f16 dot2)
// Steps processed in groups of 4: GI loads for the NEXT group issued once
// per group, H1ALL stores issued once per group. The compiler's
// `s_waitcnt vmcnt(0)` before every s_barrier drains in-flight global ops;
// batching amortizes that forced drain 4x (it hit every step before).
__launch_bounds__(384, 1)
__global__ void k_chain1(const float* __restrict__ GI1,
                         const u16* __restrict__ WHH1h,
                         const float* __restrict__ BHH1,
                         const float* __restrict__ H1I,
                         float* __restrict__ H1ALL)
{
  const int b = blockIdx.x;
  const int tid = threadIdx.x;
  __shared__ __align__(16) float h[128];
  __shared__ __align__(16) u16 hh[128];
  __shared__ float gh[384];
  if (tid < 128){ float v = H1I[b*128 + tid]; h[tid] = v; hh[tid] = f2h(v); }
  const float bias = BHH1[tid];
  u32 W[64];
  {
    const uint4* wp = (const uint4*)(WHH1h + tid*128);
    #pragma unroll
    for (int i = 0; i < 16; i++){
      uint4 v = wp[i];
      W[4*i] = v.x; W[4*i+1] = v.y; W[4*i+2] = v.z; W[4*i+3] = v.w;
    }
  }
  float cur[4][3] = {}, nxt[4][3] = {}, st[4] = {};
  if (tid < 128){
    #pragma unroll
    for (int i = 0; i < 4; i++){
      const float* gp = GI1 + (i*32 + b)*384;
      cur[i][0] = gp[tid]; cur[i][1] = gp[128+tid]; cur[i][2] = gp[256+tid];
    }
  }
  __syncthreads();
  for (int t0 = 0; t0 < T_; t0 += 4){
    if (tid < 128){
      #pragma unroll
      for (int i = 0; i < 4; i++){
        int tt = t0 + 4 + i;
        if (tt < T_){
          const float* gp = GI1 + (tt*32 + b)*384;
          nxt[i][0] = gp[tid]; nxt[i][1] = gp[128+tid]; nxt[i][2] = gp[256+tid];
        }
      }
    }
    #pragma unroll
    for (int ph = 0; ph < 4; ph++){
      if (t0 + ph >= T_) break;
      float a = bias, ab = 0.f;
      #pragma unroll
      for (int i = 0; i < 16; i++){
        uint4 hv = *(const uint4*)(hh + i*8);
        a  = dot2f(W[4*i],   hv.x, a);
        ab = dot2f(W[4*i+1], hv.y, ab);
        a  = dot2f(W[4*i+2], hv.z, a);
        ab = dot2f(W[4*i+3], hv.w, ab);
      }
      gh[tid] = a + ab;
      __syncthreads();
      if (tid < 128){
        float r = fast_sigmoid(cur[ph][0] + gh[tid]);
        float z = fast_sigmoid(cur[ph][1] + gh[128+tid]);
        float n = fast_tanh(cur[ph][2] + r*gh[256+tid]);
        float hn = (1.f - z)*n + z*h[tid];
        h[tid] = hn; hh[tid] = f2h(hn);
        st[ph] = hn;
      }
      __syncthreads();
    }
    if (tid < 128){
      #pragma unroll
      for (int ph = 0; ph < 4; ph++){
        int t = t0 + ph;
        if (t < T_) H1ALL[(t*32 + b)*128 + tid] = st[ph];
      }
      #pragma unroll
      for (int i = 0; i < 4; i++){
        cur[i][0] = nxt[i][0]; cur[i][1] = nxt[i][1]; cur[i][2] = nxt[i][2];
      }
    }
  }
}

// ---------------------------------------------------------------- K4b: h2/g2 chain (f16 dot2, batched)
__launch_bounds__(384, 1)
__global__ void k_chain2(const float* __restrict__ GI2,
                         const u16* __restrict__ WHH2h,
                         const float* __restrict__ BHH2,
                         const float* __restrict__ H2I,
                         float* __restrict__ G2)
{
  const int b = blockIdx.x;
  const int tid = threadIdx.x;
  __shared__ __align__(16) float h[128];
  __shared__ __align__(16) u16 hh[128];
  __shared__ float gh[384];
  if (tid < 128){ float v = H2I[b*128 + tid]; h[tid] = v; hh[tid] = f2h(v); }
  const float bias = BHH2[tid];
  u32 W[64];
  {
    const uint4* wp = (const uint4*)(WHH2h + tid*128);
    #pragma unroll
    for (int i = 0; i < 16; i++){
      uint4 v = wp[i];
      W[4*i] = v.x; W[4*i+1] = v.y; W[4*i+2] = v.z; W[4*i+3] = v.w;
    }
  }
  float cur[4][3] = {}, nxt[4][3] = {}, st[4] = {};
  if (tid < 128){
    #pragma unroll
    for (int i = 0; i < 4; i++){
      const float* gp = GI2 + (i*32 + b)*384;
      cur[i][0] = gp[tid]; cur[i][1] = gp[128+tid]; cur[i][2] = gp[256+tid];
    }
  }
  __syncthreads();
  for (int t0 = 0; t0 < T_; t0 += 4){
    if (tid < 128){
      #pragma unroll
      for (int i = 0; i < 4; i++){
        int tt = t0 + 4 + i;
        if (tt < T_){
          const float* gp = GI2 + (tt*32 + b)*384;
          nxt[i][0] = gp[tid]; nxt[i][1] = gp[128+tid]; nxt[i][2] = gp[256+tid];
        }
      }
    }
    #pragma unroll
    for (int ph = 0; ph < 4; ph++){
      const int t = t0 + ph;
      if (t >= T_) break;
      float a = bias, ab = 0.f;
      #pragma unroll
      for (int i = 0; i < 16; i++){
        uint4 hv = *(const uint4*)(hh + i*8);
        a  = dot2f(W[4*i],   hv.x, a);
        ab = dot2f(W[4*i+1], hv.y, ab);
        a  = dot2f(W[4*i+2], hv.z, a);
        ab = dot2f(W[4*i+3], hv.w, ab);
      }
      gh[tid] = a + ab;
      __syncthreads();
      if (tid < 128){
        float r2 = fast_sigmoid(cur[ph][0] + gh[tid]);
        float z2 = fast_sigmoid(cur[ph][1] + gh[128+tid]);
        float n2 = fast_tanh(cur[ph][2] + r2*gh[256+tid]);
        float g = (1.f - z2)*n2 + z2*h[tid];
        st[ph] = g;
        if (t > 0){ h[tid] = g; hh[tid] = f2h(g); }
      }
      __syncthreads();
    }
    if (tid < 128){
      #pragma unroll
      for (int ph = 0; ph < 4; ph++){
        int t = t0 + ph;
        if (t < T_) G2[(t*32 + b)*128 + tid] = st[ph];
      }
      #pragma unroll
      for (int i = 0; i < 4; i++){
        cur[i][0] = nxt[i][0]; cur[i][1] = nxt[i][1]; cur[i][2] = nxt[i][2];
      }
    }
  }
}

// ---------------------------------------------------------------- K5: Kp·w_k for all G2 rows
__launch_bounds__(128, 4)
__global__ void k_kp(const float* __restrict__ G2,
                     const float* __restrict__ QW, const float* __restrict__ QB,
                     const float* __restrict__ MW,
                     float* __restrict__ KPWG)
{
  __shared__ __align__(16) float X[8][128];
  __shared__ float red[8][2];
  const int tid = threadIdx.x;           // c in [0,128)
  const int base = blockIdx.x * 8;       // 796 blocks x 8 rows = 6368
  for (int o = tid; o < 1024; o += 128){
    int r = o >> 7, c = o & 127;
    X[r][c] = G2[(base + r)*128 + c];
  }
  __syncthreads();
  float acc[8];
  float bias = QB[tid];
  #pragma unroll
  for (int r = 0; r < 8; r++) acc[r] = bias;
  const float4* wp = (const float4*)(QW + tid*128);
  #pragma unroll 4
  for (int i4 = 0; i4 < 32; i4++){
    float4 wv = wp[i4];
    int kk = 4*i4;
    #pragma unroll
    for (int r = 0; r < 8; r++){
      float4 t4 = *(const float4*)(&X[r][kk]);
      acc[r] = fmaf(t4.x, wv.x, acc[r]);
      acc[r] = fmaf(t4.y, wv.y, acc[r]);
      acc[r] = fmaf(t4.z, wv.z, acc[r]);
      acc[r] = fmaf(t4.w, wv.w, acc[r]);
    }
  }
  const float wk = MW[128 + tid];
  const int lane = tid & 63, wv_ = tid >> 6;
  #pragma unroll
  for (int r = 0; r < 8; r++){
    float pv = fast_tanh(acc[r]) * wk;
    for (int off = 32; off; off >>= 1) pv += __shfl_down(pv, off);
    if (lane == 0) red[r][wv_] = pv;
  }
  __syncthreads();
  if (tid < 8) KPWG[base + tid] = red[tid][0] + red[tid][1];
}

// ---------------------------------------------------------------- K6: predict + output
__global__ void k_pred(const int* __restrict__ question,
                       const int* __restrict__ qci, const void* __restrict__ qcm,
                       const int* __restrict__ flags,
                       const float* __restrict__ EQ, const float* __restrict__ EC,
                       const float* __restrict__ QB, const float* __restrict__ MW,
                       const float* __restrict__ G2,
                       const int* __restrict__ IDX,
                       const float* __restrict__ KPWG,
                       void* __restrict__ outp)
{
  const int blk = blockIdx.x;
  const int t = blk >> 5, b = blk & 31;
  const int tid = threadIdx.x;               // 64
  __shared__ float hist[11][132];
  __shared__ float qcs[128];
  __shared__ float og[11];
  __shared__ float kpw[11];
  __shared__ int   idxs[10];
  __shared__ float kpw0s;
  const int qid = question[b*S_ + t + 1];
  const int bflag = flags[1];
  if (tid < 10) idxs[tid] = IDX[blk*10 + tid];
  __syncthreads();
  for (int o = tid; o < 11*128; o += 64){
    int k = o >> 7, c = o & 127;
    float v;
    if (k == 0) v = G2[blk*128 + c];
    else { int s = idxs[k-1]; v = (s == 0) ? 0.f : G2[(s*32 + b)*128 + c]; }
    hist[k][c] = v;
  }
  #pragma unroll
  for (int o = tid; o < 128; o += 64){
    float v = EQ[qid*128 + o];
    #pragma unroll
    for (int q = 0; q < 4; q++){
      if (readBool(qcm, qid*4 + q, bflag))
        v += EC[qci[qid*4 + q]*128 + o];
    }
    qcs[o] = v;
  }
  {
    float pv = fast_tanh(QB[tid])      * MW[128 + tid]
             + fast_tanh(QB[tid + 64]) * MW[128 + tid + 64];
    for (int off = 32; off; off >>= 1) pv += __shfl_down(pv, off);
    if (tid == 0) kpw0s = pv;
  }
  __syncthreads();
  if (tid < 11){
    float acc = 0.f;
    for (int c = 0; c < 128; c++) acc = fmaf(qcs[c], hist[tid][c], acc);
    og[tid] = acc;
    float v;
    if (tid == 0) v = KPWG[blk];
    else { int s = idxs[tid-1]; v = (s == 0) ? kpw0s : KPWG[s*32 + b]; }
    kpw[tid] = v;
  }
  __syncthreads();
  if (tid == 0){
    float tv[11];
    #pragma unroll
    for (int k = 0; k < 11; k++){
      int valid = (k == 0) || (idxs[k-1] < t);
      tv[k] = valid ? kpw[k] : NEGV;
    }
    float m = tv[0];
    #pragma unroll
    for (int k = 1; k < 11; k++) m = fmaxf(m, tv[k]);
    float den = 0.f, num = 0.f;
    #pragma unroll
    for (int k = 0; k < 11; k++){
      float e = __expf(tv[k] - m);
      den += e;
      num = fmaf(e, og[k], num);
    }
    float p = num / den;
    int col = (t == 0) ? 0 : (t + 1);
    if (flags[0]){
      ((float*)outp)[b*S_ + col] = p;
      if (t == 0) ((float*)outp)[b*S_ + 1] = 0.f;
    } else {
      ((u16*)outp)[b*S_ + col] = f2bf(p);
      if (t == 0) ((u16*)outp)[b*S_ + 1] = (u16)0;
    }
  }
}

// ---------------------------------------------------------------- launcher
extern "C" void kernel_launch(void* const* d_in, const int* in_sizes, int n_in,
                              void* d_out, int out_size, void* d_ws, size_t ws_size,
                              hipStream_t stream)
{
  (void)in_sizes; (void)n_in; (void)out_size; (void)ws_size;
  const int* question      = (const int*)d_in[0];
  const int* response      = (const int*)d_in[1];
  const void* maskp        = d_in[2];
  const int* q_neighbors   = (const int*)d_in[3];
  const int* s_neighbors   = (const int*)d_in[4];
  const int* q_concept_idx = (const int*)d_in[5];
  const void* q_concept_mask = d_in[6];

  static const int CN[NCVT] = {2560000,256000,256,98304,49152,384,384,49152,49152,
                               384,384,49152,384,16384,128,16384,128,16384,128,
                               256,1,4096,4096};
  CvtArgs ca;
  int off = 0;
  for (int i = 0; i < NCVT; i++){
    ca.s[i] = d_in[7 + i];
    ca.nreal[i] = CN[i];
    ca.off[i] = off;
    off += (CN[i] + 3) & ~3;
  }
  ca.off[NCVT] = off;
  const int total = off;

  char* ws = (char*)d_ws;
  size_t wo = 0;
  auto alloc = [&](size_t bytes) -> void* {
    void* p = ws + wo;
    wo = (wo + bytes + 255) & ~(size_t)255;
    return p;
  };
  int*   flags = (int*)  alloc(16);
  float* CVT   = (float*)alloc((size_t)total * 4);
  float* EQREC = (float*)alloc((size_t)B_*S_*D_*4);
  float* GI1   = (float*)alloc((size_t)T_*B_*384*4);
  float* GI2A  = (float*)alloc((size_t)T_*B_*384*4);
  float* H1ALL = (float*)alloc((size_t)T_*B_*D_*4);
  float* G2    = (float*)alloc((size_t)T_*B_*D_*4);
  int*   IDX   = (int*)  alloc((size_t)T_*B_*10*4);
  float* KPWG  = (float*)alloc((size_t)T_*B_*4);
  u16*   WHH1h = (u16*)  alloc(49152*2);
  u16*   WHH2h = (u16*)  alloc(49152*2);
  u16*   AWh   = (u16*)  alloc(49152*2);
  u16*   ALWh  = (u16*)  alloc(16384*2);
  u16*   WIH1h = (u16*)  alloc(98304*2);
  u16*   WIH2h = (u16*)  alloc(49152*2);

  const float* EQ   = CVT + ca.off[0];
  const float* EC   = CVT + ca.off[1];
  const float* ECOR = CVT + ca.off[2];
  const float* WIH1 = CVT + ca.off[3];
  const float* WHH1 = CVT + ca.off[4];
  const float* BIH1 = CVT + ca.off[5];
  const float* BHH1 = CVT + ca.off[6];
  const float* WIH2 = CVT + ca.off[7];
  const float* WHH2 = CVT + ca.off[8];
  const float* BIH2 = CVT + ca.off[9];
  const float* BHH2 = CVT + ca.off[10];
  const float* AW   = CVT + ca.off[11];
  const float* AB   = CVT + ca.off[12];
  const float* ALW  = CVT + ca.off[13];
  const float* ALB  = CVT + ca.off[14];
  const float* QW   = CVT + ca.off[15];
  const float* QB   = CVT + ca.off[16];
  const float* MW   = CVT + ca.off[19];
  const float* H1I  = CVT + ca.off[21];
  const float* H2I  = CVT + ca.off[22];

  k_sniff2<<<1, 256, 0, stream>>>((const u16*)d_in[7], (const unsigned char*)maskp, flags);
  k_cvt<<<(total + 255)/256, 256, 0, stream>>>(ca, flags, CVT);
  k_prep<<<384, 256, 0, stream>>>(WHH1, WHH2, AW, ALW, WIH1, WIH2,
                                  WHH1h, WHH2h, AWh, ALWh, WIH1h, WIH2h);
  k_agg<<<B_*S_/2, 256, 0, stream>>>(question, q_neighbors, s_neighbors, EQ, EC,
                                     AWh, AB, ALWh, ALB, maskp, flags, EQREC);
  k_gi1<<<dim3(T_, 4), 384, 0, stream>>>(EQREC, response, ECOR, WIH1h, BIH1, GI1);
  k_topk<<<T_*B_, 64, 0, stream>>>(question, EQ, IDX);
  k_chain1<<<B_, 384, 0, stream>>>(GI1, WHH1h, BHH1, H1I, H1ALL);
  k_gi2<<<dim3(T_, 4), 384, 0, stream>>>(H1ALL, WIH2h, BIH2, GI2A);
  k_chain2<<<B_, 384, 0, stream>>>(GI2A, WHH2h, BHH2, H2I, G2);
  k_kp<<<T_*B_/8, 128, 0, stream>>>(G2, QW, QB, MW, KPWG);
  k_pred<<<T_*B_, 64, 0, stream>>>(question, q_concept_idx, q_concept_mask, flags,
                                   EQ, EC, QB, MW, G2, IDX, KPWG, d_out);
}

// Round 12
// 620.045 us; speedup vs baseline: 2.4966x; 1.1572x over previous
//
#include <hip/hip_runtime.h>
#include <math.h>

typedef unsigned short u16;
typedef unsigned int   u32;
typedef __attribute__((ext_vector_type(2))) _Float16 half2_t;

#define B_   32
#define S_   200
#define D_   128
#define T_   199
#define NEGV (-1e30f)

__device__ __forceinline__ float bf2f(u16 u){
  union { u32 i; float f; } v; v.i = ((u32)u) << 16; return v.f;
}
__device__ __forceinline__ u16 f2bf(float f){
  union { float f; u32 i; } v; v.f = f;
  u32 x = v.i;
  return (u16)((x + 0x7fffu + ((x >> 16) & 1u)) >> 16);   // RNE
}
__device__ __forceinline__ u16 f2h(float x){
  union { _Float16 h; u16 u; } v; v.h = (_Float16)x; return v.u;
}
__device__ __forceinline__ float h2f(u16 u){
  union { u16 u; _Float16 h; } v; v.u = u; return (float)v.h;
}
__device__ __forceinline__ u32 pkh(float lo, float hi){
  return ((u32)f2h(hi) << 16) | f2h(lo);
}
// 2 MACs/instr: f32 += f16x2 . f16x2  (v_dot2_f32_f16)
__device__ __forceinline__ float dot2f(u32 w, u32 h, float acc){
#if __has_builtin(__builtin_amdgcn_fdot2)
  union { u32 u; half2_t h2; } a, b;
  a.u = w; b.u = h;
  return __builtin_amdgcn_fdot2(a.h2, b.h2, acc, false);
#else
  union { u32 u; _Float16 f[2]; } a, b;
  a.u = w; b.u = h;
  acc = fmaf((float)a.f[0], (float)b.f[0], acc);
  return fmaf((float)a.f[1], (float)b.f[1], acc);
#endif
}
__device__ __forceinline__ float fast_sigmoid(float x){ return 1.f/(1.f+__expf(-x)); }
__device__ __forceinline__ float fast_tanh(float x){
  float e = __expf(2.f*x);
  return 1.f - 2.f/(e + 1.f);
}

// bool storage modes: 0=int32, 1=u8, 2=bf16, 3=f32
__device__ __forceinline__ int readBool(const void* p, int i, int m){
  if (m == 0) return ((const int*)p)[i] != 0;
  if (m == 1) return ((const unsigned char*)p)[i] != 0;
  if (m == 2) return ((const u16*)p)[i] != 0;
  return ((const u32*)p)[i] != 0;
}

__device__ __forceinline__ float dot128f(const float* __restrict__ w,
                                         const float* __restrict__ x){
  float acc = 0.f;
  const float4* wp = (const float4*)w;
  #pragma unroll 8
  for (int i = 0; i < 32; i++){
    float4 v = wp[i]; int k = 4*i;
    acc = fmaf(v.x, x[k],   acc);
    acc = fmaf(v.y, x[k+1], acc);
    acc = fmaf(v.z, x[k+2], acc);
    acc = fmaf(v.w, x[k+3], acc);
  }
  return acc;
}

// ---------------------------------------------------------------- sniffer
__global__ void k_sniff2(const u16* __restrict__ embq_raw,
                         const unsigned char* __restrict__ mask_raw,
                         int* __restrict__ flags){
  __shared__ int bad, gt1, m4, b0;
  const int tid = threadIdx.x;
  if (tid == 0){ bad = 0; gt1 = 0; m4 = 0; b0 = 0; }
  __syncthreads();
  for (int i = tid; i < 512; i += 256){
    u16 u = embq_raw[i];
    if (u){ int e = (u >> 7) & 0xFF; if (e < 0x58 || e > 0x7F) atomicAdd(&bad, 1); }
  }
  for (int i = tid; i < 1024; i += 256){
    unsigned char c = mask_raw[i];
    if (c > 1) atomicAdd(&gt1, 1);
    if (c && (i & 3)) atomicAdd(&m4, 1);
    if (c && !(i & 3)) atomicAdd(&b0, 1);
  }
  __syncthreads();
  if (tid == 0){
    flags[0] = (bad >= 16) ? 1 : 0;
    flags[1] = gt1 ? (b0 ? 2 : 3) : (m4 ? 1 : 0);
  }
}

// ---------------------------------------------------------------- convert floats -> f32
#define NCVT 23
struct CvtArgs { const void* s[NCVT]; int off[NCVT+1]; int nreal[NCVT]; };

__global__ void k_cvt(CvtArgs a, const int* __restrict__ flags, float* __restrict__ dst){
  __shared__ int f;
  if (threadIdx.x == 0) f = flags[0];
  __syncthreads();
  int gid = blockIdx.x * 256 + threadIdx.x;
  if (gid >= a.off[NCVT]) return;
  int ai = 0;
  for (int i = 1; i < NCVT; i++) if (gid >= a.off[i]) ai = i;
  int i = gid - a.off[ai];
  float v = 0.f;
  if (i < a.nreal[ai])
    v = f ? ((const float*)a.s[ai])[i] : bf2f(((const u16*)a.s[ai])[i]);
  dst[gid] = v;
}

// ---------------------------------------------------------------- prep
// Row-per-thread weight reads were 64-distinct-cacheline loads (r11 model:
// 460K addr cycles/CU = the whole 198us of k_agg). Transpose weights so
// lane c reads COLUMN c coalesced: Wt4[(g*N + c)] (uint4) = the 8
// K-elements of output-col c, K-group g, as 4 packed f16 pairs.
__global__ void k_prep(const float* __restrict__ WHH1, const float* __restrict__ WHH2,
                       const float* __restrict__ AW,   const float* __restrict__ ALW,
                       const float* __restrict__ WIH1, const float* __restrict__ WIH2,
                       const float* __restrict__ QW,
                       u16* __restrict__ WHH1h, u16* __restrict__ WHH2h,
                       u32* __restrict__ AWt,   u32* __restrict__ ALWt,
                       u32* __restrict__ WIH1t, u32* __restrict__ WIH2t,
                       float* __restrict__ QWt)
{
  const int gid0 = blockIdx.x*256 + threadIdx.x;
  const int stride = gridDim.x*256;
  for (int g = gid0; g < 49152; g += stride){
    WHH1h[g] = f2h(WHH1[g]);
    WHH2h[g] = f2h(WHH2[g]);
  }
  // AW: 3 stages of 128x128 -> 8192 u32/stage
  for (int g = gid0; g < 24576; g += stride){
    int s = g >> 13, w = g & 8191;
    int k8 = w >> 9, r = w & 511, c = r >> 2, j = r & 3;
    const float* b = AW + s*16384 + c*128 + k8*8 + 2*j;
    AWt[g] = pkh(b[0], b[1]);
  }
  // ALW: 128x128
  for (int g = gid0; g < 8192; g += stride){
    int k8 = g >> 9, r = g & 511, c = r >> 2, j = r & 3;
    const float* b = ALW + c*128 + k8*8 + 2*j;
    ALWt[g] = pkh(b[0], b[1]);
  }
  // WIH1: 384x256 -> 32 groups x 1536
  for (int g = gid0; g < 49152; g += stride){
    int k8 = g / 1536, r = g % 1536, c = r >> 2, j = r & 3;
    const float* b = WIH1 + c*256 + k8*8 + 2*j;
    WIH1t[g] = pkh(b[0], b[1]);
  }
  // WIH2: 384x128 -> 16 groups x 1536
  for (int g = gid0; g < 24576; g += stride){
    int k8 = g / 1536, r = g % 1536, c = r >> 2, j = r & 3;
    const float* b = WIH2 + c*128 + k8*8 + 2*j;
    WIH2t[g] = pkh(b[0], b[1]);
  }
  // QW: 128x128 f32 -> float4 column layout (32 groups of 4 k)
  for (int g = gid0; g < 16384; g += stride){
    int k4 = g >> 9, r = g & 511, c = r >> 2, j = r & 3;
    QWt[g] = QW[c*128 + k4*4 + j];
  }
}

// ---------------------------------------------------------------- K1: hop aggregation (f16 dot2, coalesced Wt)
template<int ROWS>
__device__ __forceinline__ void agg_stage_h(const u16* __restrict__ tmph,
    const u32* __restrict__ Wt, const float* __restrict__ bg,
    u16* __restrict__ outh, int c)
{
  float bias = bg[c];
  float acc[ROWS];
  #pragma unroll
  for (int r = 0; r < ROWS; r++) acc[r] = bias;
  const uint4* wp = (const uint4*)Wt;
  if constexpr (ROWS <= 4){
    float acc2[ROWS];
    #pragma unroll
    for (int r = 0; r < ROWS; r++) acc2[r] = 0.f;
    #pragma unroll 4
    for (int g = 0; g < 16; g++){
      uint4 wv = wp[g*128 + c];          // coalesced: lanes consecutive
      #pragma unroll
      for (int r = 0; r < ROWS; r++){
        uint4 hv = *(const uint4*)(tmph + r*128 + g*8);   // LDS broadcast
        acc[r]  = dot2f(wv.x, hv.x, acc[r]);
        acc2[r] = dot2f(wv.y, hv.y, acc2[r]);
        acc[r]  = dot2f(wv.z, hv.z, acc[r]);
        acc2[r] = dot2f(wv.w, hv.w, acc2[r]);
      }
    }
    #pragma unroll
    for (int r = 0; r < ROWS; r++)
      outh[r*128 + c] = f2h(fast_tanh(acc[r] + acc2[r]));
  } else {
    #pragma unroll 4
    for (int g = 0; g < 16; g++){
      uint4 wv = wp[g*128 + c];
      #pragma unroll
      for (int r = 0; r < ROWS; r++){
        uint4 hv = *(const uint4*)(tmph + r*128 + g*8);
        acc[r] = dot2f(wv.x, hv.x, acc[r]);
        acc[r] = dot2f(wv.y, hv.y, acc[r]);
        acc[r] = dot2f(wv.z, hv.z, acc[r]);
        acc[r] = dot2f(wv.w, hv.w, acc[r]);
      }
    }
    #pragma unroll
    for (int r = 0; r < ROWS; r++)
      outh[r*128 + c] = f2h(fast_tanh(acc[r]));
  }
}

__launch_bounds__(256, 4)
__global__ void k_agg(const int* __restrict__ question,
                      const int* __restrict__ q_neighbors,
                      const int* __restrict__ s_neighbors,
                      const float* __restrict__ EQ,
                      const float* __restrict__ EC,
                      const u32* __restrict__ AWt,
                      const float* __restrict__ AB,
                      const u32* __restrict__ ALWt,
                      const float* __restrict__ ALB,
                      const void* __restrict__ maskp,
                      const int* __restrict__ flags,
                      float* __restrict__ EQREC)
{
  __shared__ __align__(16) u16 e0h[2][128];
  __shared__ __align__(16) u16 e1h[2][512];
  __shared__ __align__(16) u16 e2h[2][2048];
  __shared__ __align__(16) u16 tmph[2][2048];
  __shared__ int nn1[2][4]; __shared__ int nn2[2][16]; __shared__ int nn3[2][64];
  const int tid  = threadIdx.x;
  const int c    = tid & 127;
  const int half = tid >> 7;
  const int bs   = blockIdx.x*2 + half;
  const int n0   = question[bs];
  u16* tp = tmph[half];

  if (c < 4) nn1[half][c] = q_neighbors[n0*4 + c];
  __syncthreads();
  if (c < 16) nn2[half][c] = s_neighbors[nn1[half][c>>2]*4 + (c&3)];
  __syncthreads();
  if (c < 64) nn3[half][c] = q_neighbors[nn2[half][c>>2]*4 + (c&3)];
  e0h[half][c] = f2h(EQ[n0*128 + c]);
  #pragma unroll
  for (int r = 0; r < 4; r++)  e1h[half][r*128 + c] = f2h(EC[nn1[half][r]*128 + c]);
  #pragma unroll 4
  for (int r = 0; r < 16; r++) e2h[half][r*128 + c] = f2h(EQ[nn2[half][r]*128 + c]);
  __syncthreads();

  auto fill_e0 = [&](){
    float v = 0.25f*(h2f(e1h[half][c]) + h2f(e1h[half][128+c])
                   + h2f(e1h[half][256+c]) + h2f(e1h[half][384+c]))
            + h2f(e0h[half][c]);
    tp[c] = f2h(v);
  };
  auto fill_e1 = [&](){
    #pragma unroll
    for (int r = 0; r < 4; r++){
      float v = 0.25f*(h2f(e2h[half][(4*r)*128+c])   + h2f(e2h[half][(4*r+1)*128+c])
                     + h2f(e2h[half][(4*r+2)*128+c]) + h2f(e2h[half][(4*r+3)*128+c]))
              + h2f(e1h[half][r*128 + c]);
      tp[r*128 + c] = f2h(v);
    }
  };

  // i=0: j=0,1,2
  fill_e0(); __syncthreads();
  agg_stage_h<1>(tp, AWt, AB, e0h[half], c); __syncthreads();
  fill_e1(); __syncthreads();
  agg_stage_h<4>(tp, AWt + 8192, AB + 128, e1h[half], c); __syncthreads();
  #pragma unroll 2
  for (int r = 0; r < 16; r++){
    float m = 0.25f*( EC[nn3[half][4*r]*128+c]   + EC[nn3[half][4*r+1]*128+c]
                    + EC[nn3[half][4*r+2]*128+c] + EC[nn3[half][4*r+3]*128+c] );
    tp[r*128 + c] = f2h(m + h2f(e2h[half][r*128 + c]));
  }
  __syncthreads();
  agg_stage_h<16>(tp, AWt + 16384, AB + 256, e2h[half], c); __syncthreads();
  // i=1: j=0,1
  fill_e0(); __syncthreads();
  agg_stage_h<1>(tp, AWt, AB, e0h[half], c); __syncthreads();
  fill_e1(); __syncthreads();
  agg_stage_h<4>(tp, AWt + 8192, AB + 128, e1h[half], c); __syncthreads();
  // i=2: j=0
  fill_e0(); __syncthreads();
  agg_stage_h<1>(tp, AWt, AB, e0h[half], c); __syncthreads();
  // agg = tanh(e0 @ ALW.T + ALB)
  agg_stage_h<1>(e0h[half], ALWt, ALB, tp, c); __syncthreads();
  const int msk = readBool(maskp, bs, flags[1]);
  EQREC[bs*128 + c] = msk ? h2f(tp[c]) : EQ[n0*128 + c];
}

// ---------------------------------------------------------------- K2: gi1 precompute (K=256, f16 dot2, coalesced)
__launch_bounds__(384, 1)
__global__ void k_gi1(const float* __restrict__ EQREC,
                      const int* __restrict__ response,
                      const float* __restrict__ ECOR,
                      const u32* __restrict__ WIH1t,
                      const float* __restrict__ BIH1,
                      float* __restrict__ GI1)
{
  const int t  = blockIdx.x;
  const int bg = blockIdx.y;
  const int tid = threadIdx.x;
  __shared__ __align__(16) u16 X[8][256];
  for (int o = tid; o < 2048; o += 384){
    int bb = o >> 8, k = o & 255;
    int b = bg*8 + bb;
    float v = (k < 128) ? EQREC[(b*S_ + t)*128 + k]
                        : ECOR[response[b*S_ + t]*128 + (k - 128)];
    X[bb][k] = f2h(v);
  }
  __syncthreads();
  float bias = BIH1[tid];
  float acc[8];
  #pragma unroll
  for (int i = 0; i < 8; i++) acc[i] = bias;
  const uint4* wp = (const uint4*)WIH1t;   // 32 groups x 384
  #pragma unroll 4
  for (int g = 0; g < 32; g++){
    uint4 wv = wp[g*384 + tid];            // coalesced
    #pragma unroll
    for (int bb = 0; bb < 8; bb++){
      uint4 hv = *(const uint4*)(&X[bb][g*8]);   // broadcast
      acc[bb] = dot2f(wv.x, hv.x, acc[bb]);
      acc[bb] = dot2f(wv.y, hv.y, acc[bb]);
      acc[bb] = dot2f(wv.z, hv.z, acc[bb]);
      acc[bb] = dot2f(wv.w, hv.w, acc[bb]);
    }
  }
  #pragma unroll
  for (int bb = 0; bb < 8; bb++)
    GI1[(t*32 + bg*8 + bb)*384 + tid] = acc[bb];
}

// ---------------------------------------------------------------- K2b: gi2 precompute (K=128, f16 dot2, coalesced)
__launch_bounds__(384, 1)
__global__ void k_gi2(const float* __restrict__ H1ALL,
                      const u32* __restrict__ WIH2t,
                      const float* __restrict__ BIH2,
                      float* __restrict__ GI2)
{
  const int t  = blockIdx.x;
  const int bg = blockIdx.y;
  const int tid = threadIdx.x;
  __shared__ __align__(16) u16 X[8][128];
  for (int o = tid; o < 1024; o += 384){
    int bb = o >> 7, k = o & 127;
    int b = bg*8 + bb;
    X[bb][k] = f2h(H1ALL[(t*32 + b)*128 + k]);
  }
  __syncthreads();
  float bias = BIH2[tid];
  float acc[8];
  #pragma unroll
  for (int i = 0; i < 8; i++) acc[i] = bias;
  const uint4* wp = (const uint4*)WIH2t;   // 16 groups x 384
  #pragma unroll 4
  for (int g = 0; g < 16; g++){
    uint4 wv = wp[g*384 + tid];
    #pragma unroll
    for (int bb = 0; bb < 8; bb++){
      uint4 hv = *(const uint4*)(&X[bb][g*8]);
      acc[bb] = dot2f(wv.x, hv.x, acc[bb]);
      acc[bb] = dot2f(wv.y, hv.y, acc[bb]);
      acc[bb] = dot2f(wv.z, hv.z, acc[bb]);
      acc[bb] = dot2f(wv.w, hv.w, acc[bb]);
    }
  }
  #pragma unroll
  for (int bb = 0; bb < 8; bb++)
    GI2[(t*32 + bg*8 + bb)*384 + tid] = acc[bb];
}

// ---------------------------------------------------------------- K3: scores + top-10
__global__ void k_topk(const int* __restrict__ question,
                       const float* __restrict__ EQ,
                       int* __restrict__ IDX)
{
  const int blk = blockIdx.x;
  const int t = blk >> 5, b = blk & 31;
  const int tid = threadIdx.x;               // 64
  __shared__ __align__(16) float qn[128];
  const int qid = question[b*S_ + t + 1];
  for (int o = tid; o < 128; o += 64) qn[o] = EQ[qid*128 + o];
  __syncthreads();
  float val[4]; int sv[4];
  #pragma unroll
  for (int i = 0; i < 4; i++){
    int s = tid + 64*i;
    sv[i] = s;
    float v = -3.0e38f;
    if (s < S_) v = (s < t) ? dot128f(EQ + question[b*S_ + s]*128, qn) : NEGV;
    val[i] = v;
  }
  for (int r = 0; r < 10; r++){
    float bv = -3.0e38f; int bi = 0x3fffffff;
    #pragma unroll
    for (int i = 0; i < 4; i++){
      if (val[i] > bv || (val[i] == bv && sv[i] < bi)){ bv = val[i]; bi = sv[i]; }
    }
    for (int off = 32; off; off >>= 1){
      float ov = __shfl_down(bv, off);
      int   oi = __shfl_down(bi, off);
      if (ov > bv || (ov == bv && oi < bi)){ bv = ov; bi = oi; }
    }
    int win = __shfl(bi, 0);
    if (tid == 0) IDX[blk*10 + r] = win;
    #pragma unroll
    for (int i = 0; i < 4; i++) if (sv[i] == win) val[i] = -3.0e38f;
  }
}

// ---------------------------------------------------------------- K4a: h1 chain (f16 dot2, batched groups of 4)
__launch_bounds__(384, 1)
__global__ void k_chain1(const float* __restrict__ GI1,
                         const u16* __restrict__ WHH1h,
                         const float* __restrict__ BHH1,
                         const float* __restrict__ H1I,
                         float* __restrict__ H1ALL)
{
  const int b = blockIdx.x;
  const int tid = threadIdx.x;
  __shared__ __align__(16) float h[128];
  __shared__ __align__(16) u16 hh[128];
  __shared__ float gh[384];
  if (tid < 128){ float v = H1I[b*128 + tid]; h[tid] = v; hh[tid] = f2h(v); }
  const float bias = BHH1[tid];
  u32 W[64];
  {
    const uint4* wp = (const uint4*)(WHH1h + tid*128);
    #pragma unroll
    for (int i = 0; i < 16; i++){
      uint4 v = wp[i];
      W[4*i] = v.x; W[4*i+1] = v.y; W[4*i+2] = v.z; W[4*i+3] = v.w;
    }
  }
  float cur[4][3] = {}, nxt[4][3] = {}, st[4] = {};
  if (tid < 128){
    #pragma unroll
    for (int i = 0; i < 4; i++){
      const float* gp = GI1 + (i*32 + b)*384;
      cur[i][0] = gp[tid]; cur[i][1] = gp[128+tid]; cur[i][2] = gp[256+tid];
    }
  }
  __syncthreads();
  for (int t0 = 0; t0 < T_; t0 += 4){
    if (tid < 128){
      #pragma unroll
      for (int i = 0; i < 4; i++){
        int tt = t0 + 4 + i;
        if (tt < T_){
          const float* gp = GI1 + (tt*32 + b)*384;
          nxt[i][0] = gp[tid]; nxt[i][1] = gp[128+tid]; nxt[i][2] = gp[256+tid];
        }
      }
    }
    #pragma unroll
    for (int ph = 0; ph < 4; ph++){
      if (t0 + ph >= T_) break;
      float a = bias, ab = 0.f;
      #pragma unroll
      for (int i = 0; i < 16; i++){
        uint4 hv = *(const uint4*)(hh + i*8);
        a  = dot2f(W[4*i],   hv.x, a);
        ab = dot2f(W[4*i+1], hv.y, ab);
        a  = dot2f(W[4*i+2], hv.z, a);
        ab = dot2f(W[4*i+3], hv.w, ab);
      }
      gh[tid] = a + ab;
      __syncthreads();
      if (tid < 128){
        float r = fast_sigmoid(cur[ph][0] + gh[tid]);
        float z = fast_sigmoid(cur[ph][1] + gh[128+tid]);
        float n = fast_tanh(cur[ph][2] + r*gh[256+tid]);
        float hn = (1.f - z)*n + z*h[tid];
        h[tid] = hn; hh[tid] = f2h(hn);
        st[ph] = hn;
      }
      __syncthreads();
    }
    if (tid < 128){
      #pragma unroll
      for (int ph = 0; ph < 4; ph++){
        int t = t0 + ph;
        if (t < T_) H1ALL[(t*32 + b)*128 + tid] = st[ph];
      }
      #pragma unroll
      for (int i = 0; i < 4; i++){
        cur[i][0] = nxt[i][0]; cur[i][1] = nxt[i][1]; cur[i][2] = nxt[i][2];
      }
    }
  }
}

// ---------------------------------------------------------------- K4b: h2/g2 chain (f16 dot2, batched)
__launch_bounds__(384, 1)
__global__ void k_chain2(const float* __restrict__ GI2,
                         const u16* __restrict__ WHH2h,
                         const float* __restrict__ BHH2,
                         const float* __restrict__ H2I,
                         float* __restrict__ G2)
{
  const int b = blockIdx.x;
  const int tid = threadIdx.x;
  __shared__ __align__(16) float h[128];
  __shared__ __align__(16) u16 hh[128];
  __shared__ float gh[384];
  if (tid < 128){ float v = H2I[b*128 + tid]; h[tid] = v; hh[tid] = f2h(v); }
  const float bias = BHH2[tid];
  u32 W[64];
  {
    const uint4* wp = (const uint4*)(WHH2h + tid*128);
    #pragma unroll
    for (int i = 0; i < 16; i++){
      uint4 v = wp[i];
      W[4*i] = v.x; W[4*i+1] = v.y; W[4*i+2] = v.z; W[4*i+3] = v.w;
    }
  }
  float cur[4][3] = {}, nxt[4][3] = {}, st[4] = {};
  if (tid < 128){
    #pragma unroll
    for (int i = 0; i < 4; i++){
      const float* gp = GI2 + (i*32 + b)*384;
      cur[i][0] = gp[tid]; cur[i][1] = gp[128+tid]; cur[i][2] = gp[256+tid];
    }
  }
  __syncthreads();
  for (int t0 = 0; t0 < T_; t0 += 4){
    if (tid < 128){
      #pragma unroll
      for (int i = 0; i < 4; i++){
        int tt = t0 + 4 + i;
        if (tt < T_){
          const float* gp = GI2 + (tt*32 + b)*384;
          nxt[i][0] = gp[tid]; nxt[i][1] = gp[128+tid]; nxt[i][2] = gp[256+tid];
        }
      }
    }
    #pragma unroll
    for (int ph = 0; ph < 4; ph++){
      const int t = t0 + ph;
      if (t >= T_) break;
      float a = bias, ab = 0.f;
      #pragma unroll
      for (int i = 0; i < 16; i++){
        uint4 hv = *(const uint4*)(hh + i*8);
        a  = dot2f(W[4*i],   hv.x, a);
        ab = dot2f(W[4*i+1], hv.y, ab);
        a  = dot2f(W[4*i+2], hv.z, a);
        ab = dot2f(W[4*i+3], hv.w, ab);
      }
      gh[tid] = a + ab;
      __syncthreads();
      if (tid < 128){
        float r2 = fast_sigmoid(cur[ph][0] + gh[tid]);
        float z2 = fast_sigmoid(cur[ph][1] + gh[128+tid]);
        float n2 = fast_tanh(cur[ph][2] + r2*gh[256+tid]);
        float g = (1.f - z2)*n2 + z2*h[tid];
        st[ph] = g;
        if (t > 0){ h[tid] = g; hh[tid] = f2h(g); }
      }
      __syncthreads();
    }
    if (tid < 128){
      #pragma unroll
      for (int ph = 0; ph < 4; ph++){
        int t = t0 + ph;
        if (t < T_) G2[(t*32 + b)*128 + tid] = st[ph];
      }
      #pragma unroll
      for (int i = 0; i < 4; i++){
        cur[i][0] = nxt[i][0]; cur[i][1] = nxt[i][1]; cur[i][2] = nxt[i][2];
      }
    }
  }
}

// ---------------------------------------------------------------- K5: Kp·w_k for all G2 rows (coalesced QWt)
__launch_bounds__(128, 4)
__global__ void k_kp(const float* __restrict__ G2,
                     const float* __restrict__ QWt, const float* __restrict__ QB,
                     const float* __restrict__ MW,
                     float* __restrict__ KPWG)
{
  __shared__ __align__(16) float X[8][128];
  __shared__ float red[8][2];
  const int tid = threadIdx.x;           // c in [0,128)
  const int base = blockIdx.x * 8;       // 796 blocks x 8 rows = 6368
  for (int o = tid; o < 1024; o += 128){
    int r = o >> 7, c = o & 127;
    X[r][c] = G2[(base + r)*128 + c];
  }
  __syncthreads();
  float acc[8];
  float bias = QB[tid];
  #pragma unroll
  for (int r = 0; r < 8; r++) acc[r] = bias;
  const float4* wp = (const float4*)QWt;   // 32 groups x 128
  #pragma unroll 4
  for (int g = 0; g < 32; g++){
    float4 wv = wp[g*128 + tid];           // coalesced
    int kk = 4*g;
    #pragma unroll
    for (int r = 0; r < 8; r++){
      float4 t4 = *(const float4*)(&X[r][kk]);
      acc[r] = fmaf(t4.x, wv.x, acc[r]);
      acc[r] = fmaf(t4.y, wv.y, acc[r]);
      acc[r] = fmaf(t4.z, wv.z, acc[r]);
      acc[r] = fmaf(t4.w, wv.w, acc[r]);
    }
  }
  const float wk = MW[128 + tid];
  const int lane = tid & 63, wv_ = tid >> 6;
  #pragma unroll
  for (int r = 0; r < 8; r++){
    float pv = fast_tanh(acc[r]) * wk;
    for (int off = 32; off; off >>= 1) pv += __shfl_down(pv, off);
    if (lane == 0) red[r][wv_] = pv;
  }
  __syncthreads();
  if (tid < 8) KPWG[base + tid] = red[tid][0] + red[tid][1];
}

// ---------------------------------------------------------------- K6: predict + output
__global__ void k_pred(const int* __restrict__ question,
                       const int* __restrict__ qci, const void* __restrict__ qcm,
                       const int* __restrict__ flags,
                       const float* __restrict__ EQ, const float* __restrict__ EC,
                       const float* __restrict__ QB, const float* __restrict__ MW,
                       const float* __restrict__ G2,
                       const int* __restrict__ IDX,
                       const float* __restrict__ KPWG,
                       void* __restrict__ outp)
{
  const int blk = blockIdx.x;
  const int t = blk >> 5, b = blk & 31;
  const int tid = threadIdx.x;               // 64
  __shared__ float hist[11][132];
  __shared__ float qcs[128];
  __shared__ float og[11];
  __shared__ float kpw[11];
  __shared__ int   idxs[10];
  __shared__ float kpw0s;
  const int qid = question[b*S_ + t + 1];
  const int bflag = flags[1];
  if (tid < 10) idxs[tid] = IDX[blk*10 + tid];
  __syncthreads();
  for (int o = tid; o < 11*128; o += 64){
    int k = o >> 7, c = o & 127;
    float v;
    if (k == 0) v = G2[blk*128 + c];
    else { int s = idxs[k-1]; v = (s == 0) ? 0.f : G2[(s*32 + b)*128 + c]; }
    hist[k][c] = v;
  }
  #pragma unroll
  for (int o = tid; o < 128; o += 64){
    float v = EQ[qid*128 + o];
    #pragma unroll
    for (int q = 0; q < 4; q++){
      if (readBool(qcm, qid*4 + q, bflag))
        v += EC[qci[qid*4 + q]*128 + o];
    }
    qcs[o] = v;
  }
  {
    float pv = fast_tanh(QB[tid])      * MW[128 + tid]
             + fast_tanh(QB[tid + 64]) * MW[128 + tid + 64];
    for (int off = 32; off; off >>= 1) pv += __shfl_down(pv, off);
    if (tid == 0) kpw0s = pv;
  }
  __syncthreads();
  if (tid < 11){
    float acc = 0.f;
    for (int c = 0; c < 128; c++) acc = fmaf(qcs[c], hist[tid][c], acc);
    og[tid] = acc;
    float v;
    if (tid == 0) v = KPWG[blk];
    else { int s = idxs[tid-1]; v = (s == 0) ? kpw0s : KPWG[s*32 + b]; }
    kpw[tid] = v;
  }
  __syncthreads();
  if (tid == 0){
    float tv[11];
    #pragma unroll
    for (int k = 0; k < 11; k++){
      int valid = (k == 0) || (idxs[k-1] < t);
      tv[k] = valid ? kpw[k] : NEGV;
    }
    float m = tv[0];
    #pragma unroll
    for (int k = 1; k < 11; k++) m = fmaxf(m, tv[k]);
    float den = 0.f, num = 0.f;
    #pragma unroll
    for (int k = 0; k < 11; k++){
      float e = __expf(tv[k] - m);
      den += e;
      num = fmaf(e, og[k], num);
    }
    float p = num / den;
    int col = (t == 0) ? 0 : (t + 1);
    if (flags[0]){
      ((float*)outp)[b*S_ + col] = p;
      if (t == 0) ((float*)outp)[b*S_ + 1] = 0.f;
    } else {
      ((u16*)outp)[b*S_ + col] = f2bf(p);
      if (t == 0) ((u16*)outp)[b*S_ + 1] = (u16)0;
    }
  }
}

// ---------------------------------------------------------------- launcher
extern "C" void kernel_launch(void* const* d_in, const int* in_sizes, int n_in,
                              void* d_out, int out_size, void* d_ws, size_t ws_size,
                              hipStream_t stream)
{
  (void)in_sizes; (void)n_in; (void)out_size; (void)ws_size;
  const int* question      = (const int*)d_in[0];
  const int* response      = (const int*)d_in[1];
  const void* maskp        = d_in[2];
  const int* q_neighbors   = (const int*)d_in[3];
  const int* s_neighbors   = (const int*)d_in[4];
  const int* q_concept_idx = (const int*)d_in[5];
  const void* q_concept_mask = d_in[6];

  static const int CN[NCVT] = {2560000,256000,256,98304,49152,384,384,49152,49152,
                               384,384,49152,384,16384,128,16384,128,16384,128,
                               256,1,4096,4096};
  CvtArgs ca;
  int off = 0;
  for (int i = 0; i < NCVT; i++){
    ca.s[i] = d_in[7 + i];
    ca.nreal[i] = CN[i];
    ca.off[i] = off;
    off += (CN[i] + 3) & ~3;
  }
  ca.off[NCVT] = off;
  const int total = off;

  char* ws = (char*)d_ws;
  size_t wo = 0;
  auto alloc = [&](size_t bytes) -> void* {
    void* p = ws + wo;
    wo = (wo + bytes + 255) & ~(size_t)255;
    return p;
  };
  int*   flags = (int*)  alloc(16);
  float* CVT   = (float*)alloc((size_t)total * 4);
  float* EQREC = (float*)alloc((size_t)B_*S_*D_*4);
  float* GI1   = (float*)alloc((size_t)T_*B_*384*4);
  float* GI2A  = (float*)alloc((size_t)T_*B_*384*4);
  float* H1ALL = (float*)alloc((size_t)T_*B_*D_*4);
  float* G2    = (float*)alloc((size_t)T_*B_*D_*4);
  int*   IDX   = (int*)  alloc((size_t)T_*B_*10*4);
  float* KPWG  = (float*)alloc((size_t)T_*B_*4);
  u16*   WHH1h = (u16*)  alloc(49152*2);
  u16*   WHH2h = (u16*)  alloc(49152*2);
  u32*   AWt   = (u32*)  alloc(24576*4);
  u32*   ALWt  = (u32*)  alloc(8192*4);
  u32*   WIH1t = (u32*)  alloc(49152*4);
  u32*   WIH2t = (u32*)  alloc(24576*4);
  float* QWt   = (float*)alloc(16384*4);

  const float* EQ   = CVT + ca.off[0];
  const float* EC   = CVT + ca.off[1];
  const float* ECOR = CVT + ca.off[2];
  const float* WIH1 = CVT + ca.off[3];
  const float* WHH1 = CVT + ca.off[4];
  const float* BIH1 = CVT + ca.off[5];
  const float* BHH1 = CVT + ca.off[6];
  const float* WIH2 = CVT + ca.off[7];
  const float* WHH2 = CVT + ca.off[8];
  const float* BIH2 = CVT + ca.off[9];
  const float* BHH2 = CVT + ca.off[10];
  const float* AW   = CVT + ca.off[11];
  const float* AB   = CVT + ca.off[12];
  const float* ALW  = CVT + ca.off[13];
  const float* ALB  = CVT + ca.off[14];
  const float* QW   = CVT + ca.off[15];
  const float* QB   = CVT + ca.off[16];
  const float* MW   = CVT + ca.off[19];
  const float* H1I  = CVT + ca.off[21];
  const float* H2I  = CVT + ca.off[22];

  k_sniff2<<<1, 256, 0, stream>>>((const u16*)d_in[7], (const unsigned char*)maskp, flags);
  k_cvt<<<(total + 255)/256, 256, 0, stream>>>(ca, flags, CVT);
  k_prep<<<192, 256, 0, stream>>>(WHH1, WHH2, AW, ALW, WIH1, WIH2, QW,
                                  WHH1h, WHH2h, AWt, ALWt, WIH1t, WIH2t, QWt);
  k_agg<<<B_*S_/2, 256, 0, stream>>>(question, q_neighbors, s_neighbors, EQ, EC,
                                     AWt, AB, ALWt, ALB, maskp, flags, EQREC);
  k_gi1<<<dim3(T_, 4), 384, 0, stream>>>(EQREC, response, ECOR, WIH1t, BIH1, GI1);
  k_topk<<<T_*B_, 64, 0, stream>>>(question, EQ, IDX);
  k_chain1<<<B_, 384, 0, stream>>>(GI1, WHH1h, BHH1, H1I, H1ALL);
  k_gi2<<<dim3(T_, 4), 384, 0, stream>>>(H1ALL, WIH2t, BIH2, GI2A);
  k_chain2<<<B_, 384, 0, stream>>>(GI2A, WHH2h, BHH2, H2I, G2);
  k_kp<<<T_*B_/8, 128, 0, stream>>>(G2, QWt, QB, MW, KPWG);
  k_pred<<<T_*B_, 64, 0, stream>>>(question, q_concept_idx, q_concept_mask, flags,
                                   EQ, EC, QB, MW, G2, IDX, KPWG, d_out);
}